// Round 1
// baseline (4998.218 us; speedup 1.0000x reference)
//
#include <hip/hip_runtime.h>
#include <hip/hip_bf16.h>
#include <cstdint>

#define BS     2048   // B*S tokens
#define DMODEL 1024
#define RANK   512
#define NEXP   32
#define DSP    64
#define NHEAD  16
#define DHEAD  64
#define SEQ    1024
#define BATCH  2
#define HALL_N 384    // 6*DSP

// ---------------- LayerNorm (token per block, 256 thr, float4) ----------------
__global__ void ln_kernel(const float* __restrict__ x,
                          const float* __restrict__ sc,
                          const float* __restrict__ bi,
                          float* __restrict__ out) {
  int tok = blockIdx.x;
  int t = threadIdx.x; // 256
  const float4* xr = reinterpret_cast<const float4*>(x + (size_t)tok * DMODEL);
  float4 v = xr[t];
  float s = v.x + v.y + v.z + v.w;
  float q = v.x * v.x + v.y * v.y + v.z * v.z + v.w * v.w;
#pragma unroll
  for (int off = 32; off > 0; off >>= 1) {
    s += __shfl_xor(s, off);
    q += __shfl_xor(q, off);
  }
  __shared__ float red[8];
  int wid = t >> 6;
  if ((t & 63) == 0) { red[wid] = s; red[4 + wid] = q; }
  __syncthreads();
  s = red[0] + red[1] + red[2] + red[3];
  q = red[4] + red[5] + red[6] + red[7];
  float mu = s * (1.f / DMODEL);
  float var = q * (1.f / DMODEL) - mu * mu;
  float inv = rsqrtf(var + 1e-6f);
  float4 scv = reinterpret_cast<const float4*>(sc)[t];
  float4 biv = reinterpret_cast<const float4*>(bi)[t];
  float4 r;
  r.x = (v.x - mu) * inv * scv.x + biv.x;
  r.y = (v.y - mu) * inv * scv.y + biv.y;
  r.z = (v.z - mu) * inv * scv.z + biv.z;
  r.w = (v.w - mu) * inv * scv.w + biv.w;
  reinterpret_cast<float4*>(out + (size_t)tok * DMODEL)[t] = r;
}

// ---------------- emb row L2-normalize ----------------
__global__ void embnorm_kernel(const float* __restrict__ e, float* __restrict__ o) {
  int row = blockIdx.x;
  int lane = threadIdx.x; // 64
  float v = e[row * DSP + lane];
  float q = v * v;
#pragma unroll
  for (int off = 32; off > 0; off >>= 1) q += __shfl_xor(q, off);
  o[row * DSP + lane] = v / (sqrtf(q) + 1e-8f);
}

// ---------------- generic tiled GEMM: C = A[M,K]@B[K,N] (+bias) (+res) ----------------
template <bool BIAS, bool RES>
__global__ void gemm64_kernel(const float* __restrict__ A,
                              const float* __restrict__ Bm,
                              const float* __restrict__ bias,
                              const float* __restrict__ res,
                              float* __restrict__ C,
                              int M, int N, int K) {
  __shared__ float As[16][65];
  __shared__ float Bs[16][64];
  int n0 = blockIdx.x * 64;
  int m0 = blockIdx.y * 64;
  int t = threadIdx.x; // 256
  int tx = t & 15, ty = t >> 4;
  float c[4][4] = {};
  for (int k0 = 0; k0 < K; k0 += 16) {
#pragma unroll
    for (int i = 0; i < 4; i++) {
      int idx = t + i * 256;
      int m = idx >> 4, kk = idx & 15;
      As[kk][m] = A[(size_t)(m0 + m) * K + k0 + kk];
    }
#pragma unroll
    for (int i = 0; i < 4; i++) {
      int idx = t + i * 256;
      int kk = idx >> 6, nn = idx & 63;
      Bs[kk][nn] = Bm[(size_t)(k0 + kk) * N + n0 + nn];
    }
    __syncthreads();
#pragma unroll
    for (int kk = 0; kk < 16; kk++) {
      float a[4], b[4];
#pragma unroll
      for (int i = 0; i < 4; i++) a[i] = As[kk][ty + i * 16];
#pragma unroll
      for (int j = 0; j < 4; j++) b[j] = Bs[kk][tx + j * 16];
#pragma unroll
      for (int i = 0; i < 4; i++)
#pragma unroll
        for (int j = 0; j < 4; j++) c[i][j] += a[i] * b[j];
    }
    __syncthreads();
  }
#pragma unroll
  for (int i = 0; i < 4; i++) {
    int m = m0 + ty + i * 16;
#pragma unroll
    for (int j = 0; j < 4; j++) {
      int n = n0 + tx + j * 16;
      float v = c[i][j];
      if (BIAS) v += bias[n];
      if (RES) v += res[(size_t)m * N + n];
      C[(size_t)m * N + n] = v;
    }
  }
}

// ---------------- routing: softmax over 32 logits, top-4, renormalize ----------------
__global__ void route_kernel(const float* __restrict__ h, int ldh,
                             const float* __restrict__ e, // [32,64] normalized, pre-offset
                             float* __restrict__ wout) {  // [BS,32]
  int tok = blockIdx.x;
  int lane = threadIdx.x; // 64
  __shared__ float hs[DSP];
  __shared__ float es[NEXP * DSP];
  hs[lane] = h[(size_t)tok * ldh + lane];
#pragma unroll
  for (int i = 0; i < NEXP * DSP / 64; i++) es[lane + i * 64] = e[lane + i * 64];
  __syncthreads();
  float logit = -1e30f;
  if (lane < NEXP) {
    float s = 0.f;
#pragma unroll
    for (int d = 0; d < DSP; d++) s += hs[d] * es[lane * DSP + d];
    logit = s;
  }
  // softmax over lanes 0..31 (xor masks <=16 stay within the 32-group)
  float mx = logit;
#pragma unroll
  for (int off = 16; off > 0; off >>= 1) mx = fmaxf(mx, __shfl_xor(mx, off));
  float p = (lane < NEXP) ? __expf(logit - mx) : 0.f;
  float sum = p;
#pragma unroll
  for (int off = 16; off > 0; off >>= 1) sum += __shfl_xor(sum, off);
  p = p / sum;
  // top-4 (argmax iterated; tie -> lower index, matches lax.top_k)
  float val = p;
  float chosen = 0.f;
  float selsum = 0.f;
#pragma unroll
  for (int it = 0; it < 4; it++) {
    float v = val;
    int vi = lane;
#pragma unroll
    for (int off = 16; off > 0; off >>= 1) {
      float ov = __shfl_xor(v, off);
      int oi = __shfl_xor(vi, off);
      if (ov > v || (ov == v && oi < vi)) { v = ov; vi = oi; }
    }
    if (lane == vi) { chosen = p; val = -1.f; }
    selsum += v;
  }
  if (lane < NEXP) wout[(size_t)tok * NEXP + lane] = chosen / (selsum + 1e-8f);
}

// ---------------- deterministic per-expert token list (ballot compaction) ----------------
__global__ void bucket_kernel(const float* __restrict__ w, // [BS,32]
                              int* __restrict__ list,      // [32,BS]
                              int* __restrict__ count) {   // [32]
  int n = blockIdx.x;
  int lane = threadIdx.x; // 64
  int base = 0;
  for (int t0 = 0; t0 < BS; t0 += 64) {
    int tok = t0 + lane;
    bool act = (w[(size_t)tok * NEXP + n] != 0.f);
    unsigned long long mask = __ballot(act);
    int pos = __popcll(mask & ((1ull << lane) - 1ull));
    if (act) list[n * BS + base + pos] = tok;
    base += __popcll(mask);
  }
  if (lane == 0) count[n] = base;
}

// ---------------- expert-major grouped GEMM: out[t,:] += w[t,n] * X[t,:]@F[n,:,:] ----------------
__global__ void expert_gemm_kernel(const float* __restrict__ X,   // [BS,K]
                                   const float* __restrict__ F,   // [32,K,NOUT]
                                   const float* __restrict__ w,   // [BS,32]
                                   const int* __restrict__ list,  // [32,BS]
                                   const int* __restrict__ count, // [32]
                                   float* __restrict__ out,       // [BS,NOUT] (zeroed)
                                   int K, int NOUT) {
  int n = blockIdx.y;
  int cnt = count[n];
  int m0 = blockIdx.z * 64;
  if (m0 >= cnt) return;
  int n0 = blockIdx.x * 64;
  const float* Fn = F + (size_t)n * K * NOUT;
  __shared__ float Xs[16][65];
  __shared__ float Fs[16][64];
  __shared__ int toks[64];
  int t = threadIdx.x; // 256
  if (t < 64) {
    int mi = m0 + t;
    toks[t] = (mi < cnt) ? list[n * BS + mi] : -1;
  }
  __syncthreads();
  int tx = t & 15, ty = t >> 4;
  float c[4][4] = {};
  for (int k0 = 0; k0 < K; k0 += 16) {
#pragma unroll
    for (int i = 0; i < 4; i++) {
      int idx = t + i * 256;
      int m = idx >> 4, kk = idx & 15;
      int tok = toks[m];
      Xs[kk][m] = (tok >= 0) ? X[(size_t)tok * K + k0 + kk] : 0.f;
    }
#pragma unroll
    for (int i = 0; i < 4; i++) {
      int idx = t + i * 256;
      int kk = idx >> 6, nn = idx & 63;
      Fs[kk][nn] = Fn[(size_t)(k0 + kk) * NOUT + n0 + nn];
    }
    __syncthreads();
#pragma unroll
    for (int kk = 0; kk < 16; kk++) {
      float a[4], b[4];
#pragma unroll
      for (int i = 0; i < 4; i++) a[i] = Xs[kk][ty + i * 16];
#pragma unroll
      for (int j = 0; j < 4; j++) b[j] = Fs[kk][tx + j * 16];
#pragma unroll
      for (int i = 0; i < 4; i++)
#pragma unroll
        for (int j = 0; j < 4; j++) c[i][j] += a[i] * b[j];
    }
    __syncthreads();
  }
#pragma unroll
  for (int i = 0; i < 4; i++) {
    int m = ty + i * 16;
    int tok = toks[m];
    if (tok < 0) continue;
    float wt = w[(size_t)tok * NEXP + n];
#pragma unroll
    for (int j = 0; j < 4; j++) {
      atomicAdd(&out[(size_t)tok * NOUT + n0 + tx + j * 16], wt * c[i][j]);
    }
  }
}

// ---------------- causal flash attention, 1 wave/block, q-tile 64 ----------------
__global__ void attn_kernel(const float* __restrict__ Qb,
                            const float* __restrict__ Kb,
                            const float* __restrict__ Vb,
                            float* __restrict__ Ob) {
  // grid: (SEQ/64, NHEAD, BATCH), block 64
  int qt = blockIdx.x * 64;
  int h = blockIdx.y;
  int b = blockIdx.z;
  int lane = threadIdx.x;
  __shared__ float Ks[64][65];
  __shared__ float Vs[64][65];
  __shared__ float Ss[64][65];
  size_t baseQ = ((size_t)(b * SEQ + qt)) * DMODEL + h * DHEAD;
  // stage Q tile (coalesced) then read own row into regs
#pragma unroll 1
  for (int i = 0; i < 64; i++) Ss[i][lane] = Qb[baseQ + (size_t)i * DMODEL + lane];
  __syncthreads();
  float q[64];
#pragma unroll
  for (int d = 0; d < 64; d++) q[d] = Ss[lane][d] * 0.125f; // 1/sqrt(64)
  float o[64];
#pragma unroll
  for (int d = 0; d < 64; d++) o[d] = 0.f;
  float m = -1e30f, l = 0.f;
  int qr = qt + lane;
#pragma unroll 1
  for (int kt = 0; kt <= qt; kt += 64) {
    __syncthreads();
#pragma unroll 1
    for (int i = 0; i < 64; i++) {
      size_t rb = ((size_t)(b * SEQ + kt + i)) * DMODEL + h * DHEAD;
      Ks[i][lane] = Kb[rb + lane];
      Vs[i][lane] = Vb[rb + lane];
    }
    __syncthreads();
    float mt = -1e30f;
#pragma unroll 1
    for (int j = 0; j < 64; j++) {
      float s;
      if (kt + j <= qr) {
        s = 0.f;
#pragma unroll
        for (int d = 0; d < 64; d++) s += q[d] * Ks[j][d];
      } else {
        s = -1e30f;
      }
      Ss[lane][j] = s;
      mt = fmaxf(mt, s);
    }
    float mn = fmaxf(m, mt);
    float corr = __expf(m - mn);
    l *= corr;
#pragma unroll
    for (int d = 0; d < 64; d++) o[d] *= corr;
#pragma unroll 1
    for (int j = 0; j < 64; j++) {
      float p = __expf(Ss[lane][j] - mn);
      l += p;
#pragma unroll
      for (int d = 0; d < 64; d++) o[d] += p * Vs[j][d];
    }
    m = mn;
  }
  float invl = 1.f / l;
  __syncthreads();
#pragma unroll
  for (int d = 0; d < 64; d++) Ss[lane][d] = o[d] * invl;
  __syncthreads();
#pragma unroll 1
  for (int i = 0; i < 64; i++) Ob[baseQ + (size_t)i * DMODEL + lane] = Ss[i][lane];
}

// ---------------- launch ----------------
extern "C" void kernel_launch(void* const* d_in, const int* in_sizes, int n_in,
                              void* d_out, int out_size, void* d_ws, size_t ws_size,
                              hipStream_t stream) {
  const float* x    = (const float*)d_in[0];
  const float* f_qk = (const float*)d_in[1];
  const float* f_v  = (const float*)d_in[2];
  const float* r_qk = (const float*)d_in[3];
  const float* r_v  = (const float*)d_in[4];
  const float* f_kn = (const float*)d_in[5];
  const float* r_kn = (const float*)d_in[6];
  const float* nemb = (const float*)d_in[7];
  const float* W_all = (const float*)d_in[8];
  const float* b_all = (const float*)d_in[9];
  const float* W_fk  = (const float*)d_in[10];
  const float* b_fk  = (const float*)d_in[11];
  const float* W_rk  = (const float*)d_in[12];
  const float* b_rk  = (const float*)d_in[13];
  const float* W_o   = (const float*)d_in[14];
  const float* ln1s  = (const float*)d_in[15];
  const float* ln1b  = (const float*)d_in[16];
  const float* ln2s  = (const float*)d_in[17];
  const float* ln2b  = (const float*)d_in[18];

  float* ws = (float*)d_ws;
  size_t off = 0;
  auto alloc = [&](size_t nf) { float* p = ws + off; off += nf; return p; };
  float* nx    = alloc((size_t)BS * DMODEL);
  float* nx2   = alloc((size_t)BS * DMODEL);
  float* embn  = alloc(6 * NEXP * DSP);
  float* h_all = alloc((size_t)BS * HALL_N);
  float* h_fk2 = alloc((size_t)BS * DSP);
  float* h_rk2 = alloc((size_t)BS * DSP);
  float* w8    = alloc((size_t)8 * BS * NEXP);
  float* featQ = alloc((size_t)BS * RANK);   // ---- zeroed region start
  float* featK = alloc((size_t)BS * RANK);
  float* featV = alloc((size_t)BS * RANK);
  float* featN = alloc((size_t)BS * RANK);
  float* Qb    = alloc((size_t)BS * DMODEL);
  float* Kb    = alloc((size_t)BS * DMODEL);
  float* Vb    = alloc((size_t)BS * DMODEL); // ---- zeroed region end
  float* attnO = alloc((size_t)BS * DMODEL);
  float* x1    = alloc((size_t)BS * DMODEL);
  int* lists   = (int*)(ws + off); off += (size_t)8 * NEXP * BS;
  int* counts  = (int*)(ws + off); off += 8 * NEXP;

  const size_t wstr = (size_t)BS * NEXP;   // route stride in w8
  const size_t lstr = (size_t)NEXP * BS;   // route stride in lists

  embnorm_kernel<<<6 * NEXP, DSP, 0, stream>>>(nemb, embn);
  ln_kernel<<<BS, 256, 0, stream>>>(x, ln1s, ln1b, nx);
  gemm64_kernel<true, false><<<dim3(HALL_N / 64, BS / 64), 256, 0, stream>>>(
      nx, W_all, b_all, nullptr, h_all, BS, HALL_N, DMODEL);

  // zero accumulation targets: featQ..Vb contiguous
  size_t zero_flts = (size_t)4 * BS * RANK + (size_t)3 * BS * DMODEL;
  hipMemsetAsync(featQ, 0, zero_flts * sizeof(float), stream);

  // routes 0..5 from h_all segments; emb pools: fqk,fqk,fv,rqk,rqk,rv
  const int poolOf[8] = {0, 0, 1, 2, 2, 3, 4, 5};
  for (int r = 0; r < 6; r++) {
    route_kernel<<<BS, 64, 0, stream>>>(h_all + r * DSP, HALL_N,
                                        embn + poolOf[r] * NEXP * DSP,
                                        w8 + r * wstr);
    bucket_kernel<<<NEXP, 64, 0, stream>>>(w8 + r * wstr, lists + r * lstr,
                                           counts + r * NEXP);
  }

  dim3 gFeat(RANK / 64, NEXP, BS / 64);
  dim3 gRest(DMODEL / 64, NEXP, BS / 64);
  // features (K=1024 -> R=512)
  expert_gemm_kernel<<<gFeat, 256, 0, stream>>>(nx, f_qk, w8 + 0 * wstr,
                                                lists + 0 * lstr, counts + 0 * NEXP,
                                                featQ, DMODEL, RANK);
  expert_gemm_kernel<<<gFeat, 256, 0, stream>>>(nx, f_qk, w8 + 1 * wstr,
                                                lists + 1 * lstr, counts + 1 * NEXP,
                                                featK, DMODEL, RANK);
  expert_gemm_kernel<<<gFeat, 256, 0, stream>>>(nx, f_v, w8 + 2 * wstr,
                                                lists + 2 * lstr, counts + 2 * NEXP,
                                                featV, DMODEL, RANK);
  // restores (K=512 -> D=1024)
  expert_gemm_kernel<<<gRest, 256, 0, stream>>>(featQ, r_qk, w8 + 3 * wstr,
                                                lists + 3 * lstr, counts + 3 * NEXP,
                                                Qb, RANK, DMODEL);
  expert_gemm_kernel<<<gRest, 256, 0, stream>>>(featK, r_qk, w8 + 4 * wstr,
                                                lists + 4 * lstr, counts + 4 * NEXP,
                                                Kb, RANK, DMODEL);
  expert_gemm_kernel<<<gRest, 256, 0, stream>>>(featV, r_v, w8 + 5 * wstr,
                                                lists + 5 * lstr, counts + 5 * NEXP,
                                                Vb, RANK, DMODEL);

  attn_kernel<<<dim3(SEQ / 64, NHEAD, BATCH), 64, 0, stream>>>(Qb, Kb, Vb, attnO);

  // x1 = x + attnO @ W_o
  gemm64_kernel<false, true><<<dim3(DMODEL / 64, BS / 64), 256, 0, stream>>>(
      attnO, W_o, nullptr, x, x1, BS, DMODEL, DMODEL);

  // knowledge circuit
  ln_kernel<<<BS, 256, 0, stream>>>(x1, ln2s, ln2b, nx2);
  gemm64_kernel<true, false><<<dim3(1, BS / 64), 256, 0, stream>>>(
      nx2, W_fk, b_fk, nullptr, h_fk2, BS, DSP, DMODEL);
  gemm64_kernel<true, false><<<dim3(1, BS / 64), 256, 0, stream>>>(
      nx2, W_rk, b_rk, nullptr, h_rk2, BS, DSP, DMODEL);
  route_kernel<<<BS, 64, 0, stream>>>(h_fk2, DSP, embn + 4 * NEXP * DSP, w8 + 6 * wstr);
  bucket_kernel<<<NEXP, 64, 0, stream>>>(w8 + 6 * wstr, lists + 6 * lstr, counts + 6 * NEXP);
  route_kernel<<<BS, 64, 0, stream>>>(h_rk2, DSP, embn + 5 * NEXP * DSP, w8 + 7 * wstr);
  bucket_kernel<<<NEXP, 64, 0, stream>>>(w8 + 7 * wstr, lists + 7 * lstr, counts + 7 * NEXP);

  expert_gemm_kernel<<<gFeat, 256, 0, stream>>>(nx2, f_kn, w8 + 6 * wstr,
                                                lists + 6 * lstr, counts + 6 * NEXP,
                                                featN, DMODEL, RANK);
  // out = x1 + restore(featN)
  hipMemcpyAsync(d_out, x1, (size_t)BS * DMODEL * sizeof(float),
                 hipMemcpyDeviceToDevice, stream);
  expert_gemm_kernel<<<gRest, 256, 0, stream>>>(featN, r_kn, w8 + 7 * wstr,
                                                lists + 7 * lstr, counts + 7 * NEXP,
                                                (float*)d_out, RANK, DMODEL);
}

// Round 2
// 2399.886 us; speedup vs baseline: 2.0827x; 2.0827x over previous
//
#include <hip/hip_runtime.h>
#include <hip/hip_bf16.h>
#include <cstdint>

#define BS     2048   // B*S tokens
#define DMODEL 1024
#define RANK   512
#define NEXP   32
#define DSP    64
#define NHEAD  16
#define DHEAD  64
#define SEQ    1024
#define BATCH  2
#define HALL_N 384    // 6*DSP

// ---------------- LayerNorm (token per block, 256 thr, float4) ----------------
__global__ void ln_kernel(const float* __restrict__ x,
                          const float* __restrict__ sc,
                          const float* __restrict__ bi,
                          float* __restrict__ out) {
  int tok = blockIdx.x;
  int t = threadIdx.x; // 256
  const float4* xr = reinterpret_cast<const float4*>(x + (size_t)tok * DMODEL);
  float4 v = xr[t];
  float s = v.x + v.y + v.z + v.w;
  float q = v.x * v.x + v.y * v.y + v.z * v.z + v.w * v.w;
#pragma unroll
  for (int off = 32; off > 0; off >>= 1) {
    s += __shfl_xor(s, off);
    q += __shfl_xor(q, off);
  }
  __shared__ float red[8];
  int wid = t >> 6;
  if ((t & 63) == 0) { red[wid] = s; red[4 + wid] = q; }
  __syncthreads();
  s = red[0] + red[1] + red[2] + red[3];
  q = red[4] + red[5] + red[6] + red[7];
  float mu = s * (1.f / DMODEL);
  float var = q * (1.f / DMODEL) - mu * mu;
  float inv = rsqrtf(var + 1e-6f);
  float4 scv = reinterpret_cast<const float4*>(sc)[t];
  float4 biv = reinterpret_cast<const float4*>(bi)[t];
  float4 r;
  r.x = (v.x - mu) * inv * scv.x + biv.x;
  r.y = (v.y - mu) * inv * scv.y + biv.y;
  r.z = (v.z - mu) * inv * scv.z + biv.z;
  r.w = (v.w - mu) * inv * scv.w + biv.w;
  reinterpret_cast<float4*>(out + (size_t)tok * DMODEL)[t] = r;
}

// ---------------- emb row L2-normalize ----------------
__global__ void embnorm_kernel(const float* __restrict__ e, float* __restrict__ o) {
  int row = blockIdx.x;
  int lane = threadIdx.x; // 64
  float v = e[row * DSP + lane];
  float q = v * v;
#pragma unroll
  for (int off = 32; off > 0; off >>= 1) q += __shfl_xor(q, off);
  o[row * DSP + lane] = v / (sqrtf(q) + 1e-8f);
}

// ---------------- generic tiled GEMM: C = A[M,K]@B[K,N] (+bias) (+res) ----------------
template <bool BIAS, bool RES>
__global__ void gemm64_kernel(const float* __restrict__ A,
                              const float* __restrict__ Bm,
                              const float* __restrict__ bias,
                              const float* __restrict__ res,
                              float* __restrict__ C,
                              int M, int N, int K) {
  __shared__ float As[16][65];
  __shared__ float Bs[16][64];
  int n0 = blockIdx.x * 64;
  int m0 = blockIdx.y * 64;
  int t = threadIdx.x; // 256
  int tx = t & 15, ty = t >> 4;
  float c[4][4] = {};
  for (int k0 = 0; k0 < K; k0 += 16) {
#pragma unroll
    for (int i = 0; i < 4; i++) {
      int idx = t + i * 256;
      int m = idx >> 4, kk = idx & 15;
      As[kk][m] = A[(size_t)(m0 + m) * K + k0 + kk];
    }
#pragma unroll
    for (int i = 0; i < 4; i++) {
      int idx = t + i * 256;
      int kk = idx >> 6, nn = idx & 63;
      Bs[kk][nn] = Bm[(size_t)(k0 + kk) * N + n0 + nn];
    }
    __syncthreads();
#pragma unroll
    for (int kk = 0; kk < 16; kk++) {
      float a[4], b[4];
#pragma unroll
      for (int i = 0; i < 4; i++) a[i] = As[kk][ty + i * 16];
#pragma unroll
      for (int j = 0; j < 4; j++) b[j] = Bs[kk][tx + j * 16];
#pragma unroll
      for (int i = 0; i < 4; i++)
#pragma unroll
        for (int j = 0; j < 4; j++) c[i][j] += a[i] * b[j];
    }
    __syncthreads();
  }
#pragma unroll
  for (int i = 0; i < 4; i++) {
    int m = m0 + ty + i * 16;
#pragma unroll
    for (int j = 0; j < 4; j++) {
      int n = n0 + tx + j * 16;
      float v = c[i][j];
      if (BIAS) v += bias[n];
      if (RES) v += res[(size_t)m * N + n];
      C[(size_t)m * N + n] = v;
    }
  }
}

// ---------------- routing: softmax over 32 logits, top-4, renormalize ----------------
__global__ void route_kernel(const float* __restrict__ h, int ldh,
                             const float* __restrict__ e, // [32,64] normalized, pre-offset
                             float* __restrict__ wout) {  // [BS,32]
  int tok = blockIdx.x;
  int lane = threadIdx.x; // 64
  __shared__ float hs[DSP];
  __shared__ float es[NEXP * DSP];
  hs[lane] = h[(size_t)tok * ldh + lane];
#pragma unroll
  for (int i = 0; i < NEXP * DSP / 64; i++) es[lane + i * 64] = e[lane + i * 64];
  __syncthreads();
  float logit = -1e30f;
  if (lane < NEXP) {
    float s = 0.f;
#pragma unroll
    for (int d = 0; d < DSP; d++) s += hs[d] * es[lane * DSP + d];
    logit = s;
  }
  // softmax over lanes 0..31 (xor masks <=16 stay within the 32-group)
  float mx = logit;
#pragma unroll
  for (int off = 16; off > 0; off >>= 1) mx = fmaxf(mx, __shfl_xor(mx, off));
  float p = (lane < NEXP) ? __expf(logit - mx) : 0.f;
  float sum = p;
#pragma unroll
  for (int off = 16; off > 0; off >>= 1) sum += __shfl_xor(sum, off);
  p = p / sum;
  // top-4 (argmax iterated; tie -> lower index, matches lax.top_k)
  float val = p;
  float chosen = 0.f;
  float selsum = 0.f;
#pragma unroll
  for (int it = 0; it < 4; it++) {
    float v = val;
    int vi = lane;
#pragma unroll
    for (int off = 16; off > 0; off >>= 1) {
      float ov = __shfl_xor(v, off);
      int oi = __shfl_xor(vi, off);
      if (ov > v || (ov == v && oi < vi)) { v = ov; vi = oi; }
    }
    if (lane == vi) { chosen = p; val = -1.f; }
    selsum += v;
  }
  if (lane < NEXP) wout[(size_t)tok * NEXP + lane] = chosen / (selsum + 1e-8f);
}

// ---------------- deterministic per-expert token list (ballot compaction) ----------------
__global__ void bucket_kernel(const float* __restrict__ w, // [BS,32]
                              int* __restrict__ list,      // [32,BS]
                              int* __restrict__ count) {   // [32]
  int n = blockIdx.x;
  int lane = threadIdx.x; // 64
  int base = 0;
  for (int t0 = 0; t0 < BS; t0 += 64) {
    int tok = t0 + lane;
    bool act = (w[(size_t)tok * NEXP + n] != 0.f);
    unsigned long long mask = __ballot(act);
    int pos = __popcll(mask & ((1ull << lane) - 1ull));
    if (act) list[n * BS + base + pos] = tok;
    base += __popcll(mask);
  }
  if (lane == 0) count[n] = base;
}

// ---------------- expert-major grouped GEMM: out[t,:] += w[t,n] * X[t,:]@F[n,:,:] ----------------
__global__ void expert_gemm_kernel(const float* __restrict__ X,   // [BS,K]
                                   const float* __restrict__ F,   // [32,K,NOUT]
                                   const float* __restrict__ w,   // [BS,32]
                                   const int* __restrict__ list,  // [32,BS]
                                   const int* __restrict__ count, // [32]
                                   float* __restrict__ out,       // [BS,NOUT] (zeroed)
                                   int K, int NOUT) {
  int n = blockIdx.y;
  int cnt = count[n];
  int m0 = blockIdx.z * 64;
  if (m0 >= cnt) return;
  int n0 = blockIdx.x * 64;
  const float* Fn = F + (size_t)n * K * NOUT;
  __shared__ float Xs[16][65];
  __shared__ float Fs[16][64];
  __shared__ int toks[64];
  int t = threadIdx.x; // 256
  if (t < 64) {
    int mi = m0 + t;
    toks[t] = (mi < cnt) ? list[n * BS + mi] : -1;
  }
  __syncthreads();
  int tx = t & 15, ty = t >> 4;
  float c[4][4] = {};
  for (int k0 = 0; k0 < K; k0 += 16) {
#pragma unroll
    for (int i = 0; i < 4; i++) {
      int idx = t + i * 256;
      int m = idx >> 4, kk = idx & 15;
      int tok = toks[m];
      Xs[kk][m] = (tok >= 0) ? X[(size_t)tok * K + k0 + kk] : 0.f;
    }
#pragma unroll
    for (int i = 0; i < 4; i++) {
      int idx = t + i * 256;
      int kk = idx >> 6, nn = idx & 63;
      Fs[kk][nn] = Fn[(size_t)(k0 + kk) * NOUT + n0 + nn];
    }
    __syncthreads();
#pragma unroll
    for (int kk = 0; kk < 16; kk++) {
      float a[4], b[4];
#pragma unroll
      for (int i = 0; i < 4; i++) a[i] = Xs[kk][ty + i * 16];
#pragma unroll
      for (int j = 0; j < 4; j++) b[j] = Fs[kk][tx + j * 16];
#pragma unroll
      for (int i = 0; i < 4; i++)
#pragma unroll
        for (int j = 0; j < 4; j++) c[i][j] += a[i] * b[j];
    }
    __syncthreads();
  }
#pragma unroll
  for (int i = 0; i < 4; i++) {
    int m = ty + i * 16;
    int tok = toks[m];
    if (tok < 0) continue;
    float wt = w[(size_t)tok * NEXP + n];
#pragma unroll
    for (int j = 0; j < 4; j++) {
      atomicAdd(&out[(size_t)tok * NOUT + n0 + tx + j * 16], wt * c[i][j]);
    }
  }
}

// ---------------- causal flash attention ----------------
// grid: (SEQ/64, NHEAD, BATCH), block 256 (4 waves).
// Lane owns (q-row = wave*16 + lane&15, d-quarter = lane>>4): q[16], o[16] in regs.
// Score = 16-FMA partial + shfl_xor(16,32) reduce across the 4 d-group lanes.
__global__ __launch_bounds__(256) void attn_kernel(const float* __restrict__ Qb,
                                                   const float* __restrict__ Kb,
                                                   const float* __restrict__ Vb,
                                                   float* __restrict__ Ob) {
  int qt = blockIdx.x * 64;
  int h = blockIdx.y;
  int b = blockIdx.z;
  int t = threadIdx.x;
  int wave = t >> 6;
  int lane = t & 63;
  int row = wave * 16 + (lane & 15);
  int dg = lane >> 4;
  int d0 = dg * 16;
  __shared__ float Ks[64][64];
  __shared__ float Vs[64][64];
  __shared__ float Ss[64][65];
  size_t base = (size_t)(b * SEQ) * DMODEL + (size_t)h * DHEAD;
  int qr = qt + row;
  float q[16];
  {
    const float* qrow = Qb + base + (size_t)qr * DMODEL + d0;
#pragma unroll
    for (int i = 0; i < 16; i += 4) {
      float4 v = *reinterpret_cast<const float4*>(qrow + i);
      q[i] = v.x * 0.125f; q[i + 1] = v.y * 0.125f;
      q[i + 2] = v.z * 0.125f; q[i + 3] = v.w * 0.125f;
    }
  }
  float o[16];
#pragma unroll
  for (int i = 0; i < 16; i++) o[i] = 0.f;
  float m = -1e30f, l = 0.f;
  for (int kt = 0; kt <= qt; kt += 64) {
    __syncthreads();
    {
      int r = t >> 4;     // 0..15
      int sl = (t & 15) * 4;
#pragma unroll
      for (int p = 0; p < 4; p++) {
        int rr = r + p * 16;
        size_t g = base + (size_t)(kt + rr) * DMODEL + sl;
        *reinterpret_cast<float4*>(&Ks[rr][sl]) = *reinterpret_cast<const float4*>(Kb + g);
        *reinterpret_cast<float4*>(&Vs[rr][sl]) = *reinterpret_cast<const float4*>(Vb + g);
      }
    }
    __syncthreads();
    float mt = -1e30f;
#pragma unroll 4
    for (int j = 0; j < 64; j++) {
      float s = 0.f;
#pragma unroll
      for (int i = 0; i < 16; i++) s += q[i] * Ks[j][d0 + i];
      s += __shfl_xor(s, 16);
      s += __shfl_xor(s, 32);
      s = (kt + j <= qr) ? s : -1e30f;
      mt = fmaxf(mt, s);
      if (dg == 0) Ss[row][j] = s;
    }
    float mn = fmaxf(m, mt);
    float corr = __expf(m - mn);
    l *= corr;
#pragma unroll
    for (int i = 0; i < 16; i++) o[i] *= corr;
#pragma unroll 4
    for (int j = 0; j < 64; j++) {
      float p = __expf(Ss[row][j] - mn);
      l += p;
#pragma unroll
      for (int i = 0; i < 16; i++) o[i] += p * Vs[j][d0 + i];
    }
    m = mn;
  }
  float invl = 1.f / l;
  float* orow = Ob + base + (size_t)qr * DMODEL + d0;
#pragma unroll
  for (int i = 0; i < 16; i += 4) {
    float4 v;
    v.x = o[i] * invl; v.y = o[i + 1] * invl;
    v.z = o[i + 2] * invl; v.w = o[i + 3] * invl;
    *reinterpret_cast<float4*>(orow + i) = v;
  }
}

// ---------------- launch ----------------
extern "C" void kernel_launch(void* const* d_in, const int* in_sizes, int n_in,
                              void* d_out, int out_size, void* d_ws, size_t ws_size,
                              hipStream_t stream) {
  const float* x    = (const float*)d_in[0];
  const float* f_qk = (const float*)d_in[1];
  const float* f_v  = (const float*)d_in[2];
  const float* r_qk = (const float*)d_in[3];
  const float* r_v  = (const float*)d_in[4];
  const float* f_kn = (const float*)d_in[5];
  const float* r_kn = (const float*)d_in[6];
  const float* nemb = (const float*)d_in[7];
  const float* W_all = (const float*)d_in[8];
  const float* b_all = (const float*)d_in[9];
  const float* W_fk  = (const float*)d_in[10];
  const float* b_fk  = (const float*)d_in[11];
  const float* W_rk  = (const float*)d_in[12];
  const float* b_rk  = (const float*)d_in[13];
  const float* W_o   = (const float*)d_in[14];
  const float* ln1s  = (const float*)d_in[15];
  const float* ln1b  = (const float*)d_in[16];
  const float* ln2s  = (const float*)d_in[17];
  const float* ln2b  = (const float*)d_in[18];

  float* ws = (float*)d_ws;
  size_t off = 0;
  auto alloc = [&](size_t nf) { float* p = ws + off; off += nf; return p; };
  float* nx    = alloc((size_t)BS * DMODEL);
  float* nx2   = alloc((size_t)BS * DMODEL);
  float* embn  = alloc(6 * NEXP * DSP);
  float* h_all = alloc((size_t)BS * HALL_N);
  float* h_fk2 = alloc((size_t)BS * DSP);
  float* h_rk2 = alloc((size_t)BS * DSP);
  float* w8    = alloc((size_t)8 * BS * NEXP);
  float* featQ = alloc((size_t)BS * RANK);   // ---- zeroed region start
  float* featK = alloc((size_t)BS * RANK);
  float* featV = alloc((size_t)BS * RANK);
  float* featN = alloc((size_t)BS * RANK);
  float* Qb    = alloc((size_t)BS * DMODEL);
  float* Kb    = alloc((size_t)BS * DMODEL);
  float* Vb    = alloc((size_t)BS * DMODEL); // ---- zeroed region end
  float* attnO = alloc((size_t)BS * DMODEL);
  float* x1    = alloc((size_t)BS * DMODEL);
  int* lists   = (int*)(ws + off); off += (size_t)8 * NEXP * BS;
  int* counts  = (int*)(ws + off); off += 8 * NEXP;

  const size_t wstr = (size_t)BS * NEXP;   // route stride in w8
  const size_t lstr = (size_t)NEXP * BS;   // route stride in lists

  embnorm_kernel<<<6 * NEXP, DSP, 0, stream>>>(nemb, embn);
  ln_kernel<<<BS, 256, 0, stream>>>(x, ln1s, ln1b, nx);
  gemm64_kernel<true, false><<<dim3(HALL_N / 64, BS / 64), 256, 0, stream>>>(
      nx, W_all, b_all, nullptr, h_all, BS, HALL_N, DMODEL);

  // zero accumulation targets: featQ..Vb contiguous
  size_t zero_flts = (size_t)4 * BS * RANK + (size_t)3 * BS * DMODEL;
  hipMemsetAsync(featQ, 0, zero_flts * sizeof(float), stream);

  // routes 0..5 from h_all segments; emb pools: fqk,fqk,fv,rqk,rqk,rv
  const int poolOf[8] = {0, 0, 1, 2, 2, 3, 4, 5};
  for (int r = 0; r < 6; r++) {
    route_kernel<<<BS, 64, 0, stream>>>(h_all + r * DSP, HALL_N,
                                        embn + poolOf[r] * NEXP * DSP,
                                        w8 + r * wstr);
    bucket_kernel<<<NEXP, 64, 0, stream>>>(w8 + r * wstr, lists + r * lstr,
                                           counts + r * NEXP);
  }

  dim3 gFeat(RANK / 64, NEXP, BS / 64);
  dim3 gRest(DMODEL / 64, NEXP, BS / 64);
  // features (K=1024 -> R=512)
  expert_gemm_kernel<<<gFeat, 256, 0, stream>>>(nx, f_qk, w8 + 0 * wstr,
                                                lists + 0 * lstr, counts + 0 * NEXP,
                                                featQ, DMODEL, RANK);
  expert_gemm_kernel<<<gFeat, 256, 0, stream>>>(nx, f_qk, w8 + 1 * wstr,
                                                lists + 1 * lstr, counts + 1 * NEXP,
                                                featK, DMODEL, RANK);
  expert_gemm_kernel<<<gFeat, 256, 0, stream>>>(nx, f_v, w8 + 2 * wstr,
                                                lists + 2 * lstr, counts + 2 * NEXP,
                                                featV, DMODEL, RANK);
  // restores (K=512 -> D=1024)
  expert_gemm_kernel<<<gRest, 256, 0, stream>>>(featQ, r_qk, w8 + 3 * wstr,
                                                lists + 3 * lstr, counts + 3 * NEXP,
                                                Qb, RANK, DMODEL);
  expert_gemm_kernel<<<gRest, 256, 0, stream>>>(featK, r_qk, w8 + 4 * wstr,
                                                lists + 4 * lstr, counts + 4 * NEXP,
                                                Kb, RANK, DMODEL);
  expert_gemm_kernel<<<gRest, 256, 0, stream>>>(featV, r_v, w8 + 5 * wstr,
                                                lists + 5 * lstr, counts + 5 * NEXP,
                                                Vb, RANK, DMODEL);

  attn_kernel<<<dim3(SEQ / 64, NHEAD, BATCH), 256, 0, stream>>>(Qb, Kb, Vb, attnO);

  // x1 = x + attnO @ W_o
  gemm64_kernel<false, true><<<dim3(DMODEL / 64, BS / 64), 256, 0, stream>>>(
      attnO, W_o, nullptr, x, x1, BS, DMODEL, DMODEL);

  // knowledge circuit
  ln_kernel<<<BS, 256, 0, stream>>>(x1, ln2s, ln2b, nx2);
  gemm64_kernel<true, false><<<dim3(1, BS / 64), 256, 0, stream>>>(
      nx2, W_fk, b_fk, nullptr, h_fk2, BS, DSP, DMODEL);
  gemm64_kernel<true, false><<<dim3(1, BS / 64), 256, 0, stream>>>(
      nx2, W_rk, b_rk, nullptr, h_rk2, BS, DSP, DMODEL);
  route_kernel<<<BS, 64, 0, stream>>>(h_fk2, DSP, embn + 4 * NEXP * DSP, w8 + 6 * wstr);
  bucket_kernel<<<NEXP, 64, 0, stream>>>(w8 + 6 * wstr, lists + 6 * lstr, counts + 6 * NEXP);
  route_kernel<<<BS, 64, 0, stream>>>(h_rk2, DSP, embn + 5 * NEXP * DSP, w8 + 7 * wstr);
  bucket_kernel<<<NEXP, 64, 0, stream>>>(w8 + 7 * wstr, lists + 7 * lstr, counts + 7 * NEXP);

  expert_gemm_kernel<<<gFeat, 256, 0, stream>>>(nx2, f_kn, w8 + 6 * wstr,
                                                lists + 6 * lstr, counts + 6 * NEXP,
                                                featN, DMODEL, RANK);
  // out = x1 + restore(featN)
  hipMemcpyAsync(d_out, x1, (size_t)BS * DMODEL * sizeof(float),
                 hipMemcpyDeviceToDevice, stream);
  expert_gemm_kernel<<<gRest, 256, 0, stream>>>(featN, r_kn, w8 + 7 * wstr,
                                                lists + 7 * lstr, counts + 7 * NEXP,
                                                (float*)d_out, RANK, DMODEL);
}

// Round 3
// 1207.834 us; speedup vs baseline: 4.1382x; 1.9869x over previous
//
#include <hip/hip_runtime.h>
#include <hip/hip_bf16.h>
#include <cstdint>

#define BS     2048   // B*S tokens
#define DMODEL 1024
#define RANK   512
#define NEXP   32
#define DSP    64
#define NHEAD  16
#define DHEAD  64
#define SEQ    1024
#define BATCH  2
#define HALL_N 384    // 6*DSP

typedef unsigned short u16;
typedef __attribute__((ext_vector_type(8))) short short8;
typedef __attribute__((ext_vector_type(4))) float f32x4;

__device__ __forceinline__ u16 bfbits(float x) {
  __hip_bfloat16 h = __float2bfloat16(x);
  return __builtin_bit_cast(u16, h);
}

// ---------------- LayerNorm (token per block, 256 thr, float4) ----------------
__global__ void ln_kernel(const float* __restrict__ x,
                          const float* __restrict__ sc,
                          const float* __restrict__ bi,
                          float* __restrict__ out) {
  int tok = blockIdx.x;
  int t = threadIdx.x; // 256
  const float4* xr = reinterpret_cast<const float4*>(x + (size_t)tok * DMODEL);
  float4 v = xr[t];
  float s = v.x + v.y + v.z + v.w;
  float q = v.x * v.x + v.y * v.y + v.z * v.z + v.w * v.w;
#pragma unroll
  for (int off = 32; off > 0; off >>= 1) {
    s += __shfl_xor(s, off);
    q += __shfl_xor(q, off);
  }
  __shared__ float red[8];
  int wid = t >> 6;
  if ((t & 63) == 0) { red[wid] = s; red[4 + wid] = q; }
  __syncthreads();
  s = red[0] + red[1] + red[2] + red[3];
  q = red[4] + red[5] + red[6] + red[7];
  float mu = s * (1.f / DMODEL);
  float var = q * (1.f / DMODEL) - mu * mu;
  float inv = rsqrtf(var + 1e-6f);
  float4 scv = reinterpret_cast<const float4*>(sc)[t];
  float4 biv = reinterpret_cast<const float4*>(bi)[t];
  float4 r;
  r.x = (v.x - mu) * inv * scv.x + biv.x;
  r.y = (v.y - mu) * inv * scv.y + biv.y;
  r.z = (v.z - mu) * inv * scv.z + biv.z;
  r.w = (v.w - mu) * inv * scv.w + biv.w;
  reinterpret_cast<float4*>(out + (size_t)tok * DMODEL)[t] = r;
}

// ---------------- emb row L2-normalize ----------------
__global__ void embnorm_kernel(const float* __restrict__ e, float* __restrict__ o) {
  int row = blockIdx.x;
  int lane = threadIdx.x; // 64
  float v = e[row * DSP + lane];
  float q = v * v;
#pragma unroll
  for (int off = 32; off > 0; off >>= 1) q += __shfl_xor(q, off);
  o[row * DSP + lane] = v / (sqrtf(q) + 1e-8f);
}

// ---------------- generic tiled GEMM: C = A[M,K]@B[K,N] (+bias) (+res) ----------------
template <bool BIAS, bool RES>
__global__ void gemm64_kernel(const float* __restrict__ A,
                              const float* __restrict__ Bm,
                              const float* __restrict__ bias,
                              const float* __restrict__ res,
                              float* __restrict__ C,
                              int M, int N, int K) {
  __shared__ float As[16][65];
  __shared__ float Bs[16][64];
  int n0 = blockIdx.x * 64;
  int m0 = blockIdx.y * 64;
  int t = threadIdx.x; // 256
  int tx = t & 15, ty = t >> 4;
  float c[4][4] = {};
  for (int k0 = 0; k0 < K; k0 += 16) {
#pragma unroll
    for (int i = 0; i < 4; i++) {
      int idx = t + i * 256;
      int m = idx >> 4, kk = idx & 15;
      As[kk][m] = A[(size_t)(m0 + m) * K + k0 + kk];
    }
#pragma unroll
    for (int i = 0; i < 4; i++) {
      int idx = t + i * 256;
      int kk = idx >> 6, nn = idx & 63;
      Bs[kk][nn] = Bm[(size_t)(k0 + kk) * N + n0 + nn];
    }
    __syncthreads();
#pragma unroll
    for (int kk = 0; kk < 16; kk++) {
      float a[4], b[4];
#pragma unroll
      for (int i = 0; i < 4; i++) a[i] = As[kk][ty + i * 16];
#pragma unroll
      for (int j = 0; j < 4; j++) b[j] = Bs[kk][tx + j * 16];
#pragma unroll
      for (int i = 0; i < 4; i++)
#pragma unroll
        for (int j = 0; j < 4; j++) c[i][j] += a[i] * b[j];
    }
    __syncthreads();
  }
#pragma unroll
  for (int i = 0; i < 4; i++) {
    int m = m0 + ty + i * 16;
#pragma unroll
    for (int j = 0; j < 4; j++) {
      int n = n0 + tx + j * 16;
      float v = c[i][j];
      if (BIAS) v += bias[n];
      if (RES) v += res[(size_t)m * N + n];
      C[(size_t)m * N + n] = v;
    }
  }
}

// ---------------- routing: softmax over 32 logits, top-4, renormalize ----------------
__global__ void route_kernel(const float* __restrict__ h, int ldh,
                             const float* __restrict__ e, // [32,64] normalized, pre-offset
                             float* __restrict__ wout) {  // [BS,32]
  int tok = blockIdx.x;
  int lane = threadIdx.x; // 64
  __shared__ float hs[DSP];
  __shared__ float es[NEXP * DSP];
  hs[lane] = h[(size_t)tok * ldh + lane];
#pragma unroll
  for (int i = 0; i < NEXP * DSP / 64; i++) es[lane + i * 64] = e[lane + i * 64];
  __syncthreads();
  float logit = -1e30f;
  if (lane < NEXP) {
    float s = 0.f;
#pragma unroll
    for (int d = 0; d < DSP; d++) s += hs[d] * es[lane * DSP + d];
    logit = s;
  }
  float mx = logit;
#pragma unroll
  for (int off = 16; off > 0; off >>= 1) mx = fmaxf(mx, __shfl_xor(mx, off));
  float p = (lane < NEXP) ? __expf(logit - mx) : 0.f;
  float sum = p;
#pragma unroll
  for (int off = 16; off > 0; off >>= 1) sum += __shfl_xor(sum, off);
  p = p / sum;
  float val = p;
  float chosen = 0.f;
  float selsum = 0.f;
#pragma unroll
  for (int it = 0; it < 4; it++) {
    float v = val;
    int vi = lane;
#pragma unroll
    for (int off = 16; off > 0; off >>= 1) {
      float ov = __shfl_xor(v, off);
      int oi = __shfl_xor(vi, off);
      if (ov > v || (ov == v && oi < vi)) { v = ov; vi = oi; }
    }
    if (lane == vi) { chosen = p; val = -1.f; }
    selsum += v;
  }
  if (lane < NEXP) wout[(size_t)tok * NEXP + lane] = chosen / (selsum + 1e-8f);
}

// ---------------- deterministic per-expert token list (ballot compaction) ----------------
__global__ void bucket_kernel(const float* __restrict__ w, // [BS,32]
                              int* __restrict__ list,      // [32,BS]
                              int* __restrict__ count) {   // [32]
  int n = blockIdx.x;
  int lane = threadIdx.x; // 64
  int base = 0;
  for (int t0 = 0; t0 < BS; t0 += 64) {
    int tok = t0 + lane;
    bool act = (w[(size_t)tok * NEXP + n] != 0.f);
    unsigned long long mask = __ballot(act);
    int pos = __popcll(mask & ((1ull << lane) - 1ull));
    if (act) list[n * BS + base + pos] = tok;
    base += __popcll(mask);
  }
  if (lane == 0) count[n] = base;
}

// ---------------- f32 -> bf16 elementwise (4 elems/thread) ----------------
__global__ void f2b_kernel(const float* __restrict__ in, u16* __restrict__ out, int n4) {
  int i = blockIdx.x * 256 + threadIdx.x;
  if (i >= n4) return;
  float4 v = reinterpret_cast<const float4*>(in)[i];
  ushort4 o;
  o.x = bfbits(v.x); o.y = bfbits(v.y); o.z = bfbits(v.z); o.w = bfbits(v.w);
  reinterpret_cast<ushort4*>(out)[i] = o;
}

// ---------------- weight convert+transpose: F[e][K][NOUT] f32 -> FT[e][NOUT][K] bf16 ----
__global__ void wconv_kernel(const float* __restrict__ F, u16* __restrict__ FT,
                             int K, int NOUT) {
  int e = blockIdx.z;
  int n0 = blockIdx.x * 64, k0 = blockIdx.y * 64;
  const float* Fe = F + (size_t)e * K * NOUT;
  u16* FTe = FT + (size_t)e * K * NOUT;
  __shared__ u16 tile[64][72];
  int t = threadIdx.x; // 256
  int kr = t >> 4, nc = (t & 15) * 4;
#pragma unroll
  for (int p = 0; p < 4; p++) {
    int kk = kr + p * 16;
    float4 v = *reinterpret_cast<const float4*>(Fe + (size_t)(k0 + kk) * NOUT + n0 + nc);
    tile[nc + 0][kk] = bfbits(v.x);
    tile[nc + 1][kk] = bfbits(v.y);
    tile[nc + 2][kk] = bfbits(v.z);
    tile[nc + 3][kk] = bfbits(v.w);
  }
  __syncthreads();
  int nr = t >> 2, c0 = (t & 3) * 16;
  u16* dst = FTe + (size_t)(n0 + nr) * K + k0 + c0;
  *reinterpret_cast<short8*>(dst) = *reinterpret_cast<const short8*>(&tile[nr][c0]);
  *reinterpret_cast<short8*>(dst + 8) = *reinterpret_cast<const short8*>(&tile[nr][c0 + 8]);
}

// ---------------- expert-major grouped GEMM (bf16 MFMA) ----------------
// out[t,:] += w[t,n] * Xb[t,:] @ F[n]  with FT[n] = F[n]^T ([NOUT][K], k-contiguous)
__global__ __launch_bounds__(256) void expert_gemm_mfma(
    const u16* __restrict__ Xb,   // [BS][K] bf16
    const u16* __restrict__ FT,   // [32][NOUT][K] bf16
    const float* __restrict__ w,  // [BS,32]
    const int* __restrict__ list, // [32,BS]
    const int* __restrict__ count,// [32]
    float* __restrict__ out,      // [BS,NOUT] fp32 (zeroed)
    int K, int NOUT) {
  int n = blockIdx.y;
  int cnt = count[n];
  int m0 = blockIdx.z * 64;
  if (m0 >= cnt) return;
  int n0 = blockIdx.x * 64;
  __shared__ u16 Xs[64][72];
  __shared__ u16 Fs[64][72];
  __shared__ int toks[64];
  int t = threadIdx.x;
  if (t < 64) toks[t] = (m0 + t < cnt) ? list[n * BS + m0 + t] : -1;
  __syncthreads();
  const u16* FTe = FT + ((size_t)n * NOUT + n0) * K;
  int wave = t >> 6, lane = t & 63;
  int wm = wave >> 1, wn = wave & 1;
  int lr = lane & 15, kg = lane >> 4;
  f32x4 acc[2][2] = {};
  int srow = t >> 2, sc = (t & 3) * 16;
  int tok = toks[srow];
  const u16* xrow = Xb + (size_t)(tok < 0 ? 0 : tok) * K + sc;
  const u16* frow = FTe + (size_t)srow * K + sc;
  for (int k0 = 0; k0 < K; k0 += 64) {
    short8 xv0 = {}, xv1 = {};
    if (tok >= 0) {
      xv0 = *reinterpret_cast<const short8*>(xrow + k0);
      xv1 = *reinterpret_cast<const short8*>(xrow + k0 + 8);
    }
    short8 fv0 = *reinterpret_cast<const short8*>(frow + k0);
    short8 fv1 = *reinterpret_cast<const short8*>(frow + k0 + 8);
    __syncthreads();
    *reinterpret_cast<short8*>(&Xs[srow][sc]) = xv0;
    *reinterpret_cast<short8*>(&Xs[srow][sc + 8]) = xv1;
    *reinterpret_cast<short8*>(&Fs[srow][sc]) = fv0;
    *reinterpret_cast<short8*>(&Fs[srow][sc + 8]) = fv1;
    __syncthreads();
#pragma unroll
    for (int kk = 0; kk < 2; kk++) {
      short8 a0 = *reinterpret_cast<const short8*>(&Xs[wm * 32 + lr][kk * 32 + kg * 8]);
      short8 a1 = *reinterpret_cast<const short8*>(&Xs[wm * 32 + 16 + lr][kk * 32 + kg * 8]);
      short8 b0 = *reinterpret_cast<const short8*>(&Fs[wn * 32 + lr][kk * 32 + kg * 8]);
      short8 b1 = *reinterpret_cast<const short8*>(&Fs[wn * 32 + 16 + lr][kk * 32 + kg * 8]);
      acc[0][0] = __builtin_amdgcn_mfma_f32_16x16x32_bf16(a0, b0, acc[0][0], 0, 0, 0);
      acc[0][1] = __builtin_amdgcn_mfma_f32_16x16x32_bf16(a0, b1, acc[0][1], 0, 0, 0);
      acc[1][0] = __builtin_amdgcn_mfma_f32_16x16x32_bf16(a1, b0, acc[1][0], 0, 0, 0);
      acc[1][1] = __builtin_amdgcn_mfma_f32_16x16x32_bf16(a1, b1, acc[1][1], 0, 0, 0);
    }
  }
#pragma unroll
  for (int mi = 0; mi < 2; mi++) {
#pragma unroll
    for (int j = 0; j < 4; j++) {
      int row = wm * 32 + mi * 16 + kg * 4 + j;
      int tk = toks[row];
      if (tk < 0) continue;
      float wt = w[(size_t)tk * NEXP + n];
#pragma unroll
      for (int ni = 0; ni < 2; ni++) {
        int col = n0 + wn * 32 + ni * 16 + lr;
        atomicAdd(&out[(size_t)tk * NOUT + col], wt * acc[mi][ni][j]);
      }
    }
  }
}

// ---------------- causal flash attention ----------------
__global__ __launch_bounds__(256) void attn_kernel(const float* __restrict__ Qb,
                                                   const float* __restrict__ Kb,
                                                   const float* __restrict__ Vb,
                                                   float* __restrict__ Ob) {
  int qt = blockIdx.x * 64;
  int h = blockIdx.y;
  int b = blockIdx.z;
  int t = threadIdx.x;
  int wave = t >> 6;
  int lane = t & 63;
  int row = wave * 16 + (lane & 15);
  int dg = lane >> 4;
  int d0 = dg * 16;
  __shared__ float Ks[64][64];
  __shared__ float Vs[64][64];
  __shared__ float Ss[64][65];
  size_t base = (size_t)(b * SEQ) * DMODEL + (size_t)h * DHEAD;
  int qr = qt + row;
  float q[16];
  {
    const float* qrow = Qb + base + (size_t)qr * DMODEL + d0;
#pragma unroll
    for (int i = 0; i < 16; i += 4) {
      float4 v = *reinterpret_cast<const float4*>(qrow + i);
      q[i] = v.x * 0.125f; q[i + 1] = v.y * 0.125f;
      q[i + 2] = v.z * 0.125f; q[i + 3] = v.w * 0.125f;
    }
  }
  float o[16];
#pragma unroll
  for (int i = 0; i < 16; i++) o[i] = 0.f;
  float m = -1e30f, l = 0.f;
  for (int kt = 0; kt <= qt; kt += 64) {
    __syncthreads();
    {
      int r = t >> 4;
      int sl = (t & 15) * 4;
#pragma unroll
      for (int p = 0; p < 4; p++) {
        int rr = r + p * 16;
        size_t g = base + (size_t)(kt + rr) * DMODEL + sl;
        *reinterpret_cast<float4*>(&Ks[rr][sl]) = *reinterpret_cast<const float4*>(Kb + g);
        *reinterpret_cast<float4*>(&Vs[rr][sl]) = *reinterpret_cast<const float4*>(Vb + g);
      }
    }
    __syncthreads();
    float mt = -1e30f;
#pragma unroll 4
    for (int j = 0; j < 64; j++) {
      float s = 0.f;
#pragma unroll
      for (int i = 0; i < 16; i++) s += q[i] * Ks[j][d0 + i];
      s += __shfl_xor(s, 16);
      s += __shfl_xor(s, 32);
      s = (kt + j <= qr) ? s : -1e30f;
      mt = fmaxf(mt, s);
      if (dg == 0) Ss[row][j] = s;
    }
    float mn = fmaxf(m, mt);
    float corr = __expf(m - mn);
    l *= corr;
#pragma unroll
    for (int i = 0; i < 16; i++) o[i] *= corr;
#pragma unroll 4
    for (int j = 0; j < 64; j++) {
      float p = __expf(Ss[row][j] - mn);
      l += p;
#pragma unroll
      for (int i = 0; i < 16; i++) o[i] += p * Vs[j][d0 + i];
    }
    m = mn;
  }
  float invl = 1.f / l;
  float* orow = Ob + base + (size_t)qr * DMODEL + d0;
#pragma unroll
  for (int i = 0; i < 16; i += 4) {
    float4 v;
    v.x = o[i] * invl; v.y = o[i + 1] * invl;
    v.z = o[i + 2] * invl; v.w = o[i + 3] * invl;
    *reinterpret_cast<float4*>(orow + i) = v;
  }
}

// ---------------- launch ----------------
extern "C" void kernel_launch(void* const* d_in, const int* in_sizes, int n_in,
                              void* d_out, int out_size, void* d_ws, size_t ws_size,
                              hipStream_t stream) {
  const float* x    = (const float*)d_in[0];
  const float* f_qk = (const float*)d_in[1];
  const float* f_v  = (const float*)d_in[2];
  const float* r_qk = (const float*)d_in[3];
  const float* r_v  = (const float*)d_in[4];
  const float* f_kn = (const float*)d_in[5];
  const float* r_kn = (const float*)d_in[6];
  const float* nemb = (const float*)d_in[7];
  const float* W_all = (const float*)d_in[8];
  const float* b_all = (const float*)d_in[9];
  const float* W_fk  = (const float*)d_in[10];
  const float* b_fk  = (const float*)d_in[11];
  const float* W_rk  = (const float*)d_in[12];
  const float* b_rk  = (const float*)d_in[13];
  const float* W_o   = (const float*)d_in[14];
  const float* ln1s  = (const float*)d_in[15];
  const float* ln1b  = (const float*)d_in[16];
  const float* ln2s  = (const float*)d_in[17];
  const float* ln2b  = (const float*)d_in[18];

  float* ws = (float*)d_ws;
  size_t off = 0;
  auto alloc = [&](size_t nf) { float* p = ws + off; off += nf; return p; };
  float* nx    = alloc((size_t)BS * DMODEL);
  float* nx2   = alloc((size_t)BS * DMODEL);
  float* embn  = alloc(6 * NEXP * DSP);
  float* h_all = alloc((size_t)BS * HALL_N);
  float* h_fk2 = alloc((size_t)BS * DSP);
  float* h_rk2 = alloc((size_t)BS * DSP);
  float* w8    = alloc((size_t)8 * BS * NEXP);
  float* featQ = alloc((size_t)BS * RANK);   // ---- zeroed region start
  float* featK = alloc((size_t)BS * RANK);
  float* featV = alloc((size_t)BS * RANK);
  float* featN = alloc((size_t)BS * RANK);
  float* Qb    = alloc((size_t)BS * DMODEL);
  float* Kb    = alloc((size_t)BS * DMODEL);
  float* Vb    = alloc((size_t)BS * DMODEL); // ---- zeroed region end
  float* attnO = alloc((size_t)BS * DMODEL);
  float* x1    = alloc((size_t)BS * DMODEL);
  int* lists   = (int*)(ws + off); off += (size_t)8 * NEXP * BS;
  int* counts  = (int*)(ws + off); off += 8 * NEXP;
  // bf16 buffers (u16), allocated in float units
  u16* nxb  = (u16*)(ws + off); off += (size_t)BS * DMODEL / 2;
  u16* fqb  = (u16*)(ws + off); off += (size_t)BS * RANK / 2;
  u16* fkb  = (u16*)(ws + off); off += (size_t)BS * RANK / 2;
  u16* fvb  = (u16*)(ws + off); off += (size_t)BS * RANK / 2;
  u16* wbuf = (u16*)(ws + off); off += (size_t)NEXP * DMODEL * RANK / 2;

  const size_t wstr = (size_t)BS * NEXP;
  const size_t lstr = (size_t)NEXP * BS;

  embnorm_kernel<<<6 * NEXP, DSP, 0, stream>>>(nemb, embn);
  ln_kernel<<<BS, 256, 0, stream>>>(x, ln1s, ln1b, nx);
  gemm64_kernel<true, false><<<dim3(HALL_N / 64, BS / 64), 256, 0, stream>>>(
      nx, W_all, b_all, nullptr, h_all, BS, HALL_N, DMODEL);

  size_t zero_flts = (size_t)4 * BS * RANK + (size_t)3 * BS * DMODEL;
  hipMemsetAsync(featQ, 0, zero_flts * sizeof(float), stream);

  const int poolOf[8] = {0, 0, 1, 2, 2, 3, 4, 5};
  for (int r = 0; r < 6; r++) {
    route_kernel<<<BS, 64, 0, stream>>>(h_all + r * DSP, HALL_N,
                                        embn + poolOf[r] * NEXP * DSP,
                                        w8 + r * wstr);
    bucket_kernel<<<NEXP, 64, 0, stream>>>(w8 + r * wstr, lists + r * lstr,
                                           counts + r * NEXP);
  }

  f2b_kernel<<<(BS * DMODEL / 4 + 255) / 256, 256, 0, stream>>>(nx, nxb, BS * DMODEL / 4);

  dim3 gFeat(RANK / 64, NEXP, BS / 64);
  dim3 gRest(DMODEL / 64, NEXP, BS / 64);
  dim3 gWF(RANK / 64, DMODEL / 64, NEXP);   // features: K=DMODEL, NOUT=RANK
  dim3 gWR(DMODEL / 64, RANK / 64, NEXP);   // restores: K=RANK, NOUT=DMODEL

  // features (K=1024 -> R=512)
  wconv_kernel<<<gWF, 256, 0, stream>>>(f_qk, wbuf, DMODEL, RANK);
  expert_gemm_mfma<<<gFeat, 256, 0, stream>>>(nxb, wbuf, w8 + 0 * wstr,
                                              lists + 0 * lstr, counts + 0 * NEXP,
                                              featQ, DMODEL, RANK);
  expert_gemm_mfma<<<gFeat, 256, 0, stream>>>(nxb, wbuf, w8 + 1 * wstr,
                                              lists + 1 * lstr, counts + 1 * NEXP,
                                              featK, DMODEL, RANK);
  wconv_kernel<<<gWF, 256, 0, stream>>>(f_v, wbuf, DMODEL, RANK);
  expert_gemm_mfma<<<gFeat, 256, 0, stream>>>(nxb, wbuf, w8 + 2 * wstr,
                                              lists + 2 * lstr, counts + 2 * NEXP,
                                              featV, DMODEL, RANK);
  // bf16 feats
  f2b_kernel<<<(BS * RANK / 4 + 255) / 256, 256, 0, stream>>>(featQ, fqb, BS * RANK / 4);
  f2b_kernel<<<(BS * RANK / 4 + 255) / 256, 256, 0, stream>>>(featK, fkb, BS * RANK / 4);
  f2b_kernel<<<(BS * RANK / 4 + 255) / 256, 256, 0, stream>>>(featV, fvb, BS * RANK / 4);
  // restores (K=512 -> D=1024)
  wconv_kernel<<<gWR, 256, 0, stream>>>(r_qk, wbuf, RANK, DMODEL);
  expert_gemm_mfma<<<gRest, 256, 0, stream>>>(fqb, wbuf, w8 + 3 * wstr,
                                              lists + 3 * lstr, counts + 3 * NEXP,
                                              Qb, RANK, DMODEL);
  expert_gemm_mfma<<<gRest, 256, 0, stream>>>(fkb, wbuf, w8 + 4 * wstr,
                                              lists + 4 * lstr, counts + 4 * NEXP,
                                              Kb, RANK, DMODEL);
  wconv_kernel<<<gWR, 256, 0, stream>>>(r_v, wbuf, RANK, DMODEL);
  expert_gemm_mfma<<<gRest, 256, 0, stream>>>(fvb, wbuf, w8 + 5 * wstr,
                                              lists + 5 * lstr, counts + 5 * NEXP,
                                              Vb, RANK, DMODEL);

  attn_kernel<<<dim3(SEQ / 64, NHEAD, BATCH), 256, 0, stream>>>(Qb, Kb, Vb, attnO);

  gemm64_kernel<false, true><<<dim3(DMODEL / 64, BS / 64), 256, 0, stream>>>(
      attnO, W_o, nullptr, x, x1, BS, DMODEL, DMODEL);

  // knowledge circuit
  ln_kernel<<<BS, 256, 0, stream>>>(x1, ln2s, ln2b, nx2);
  gemm64_kernel<true, false><<<dim3(1, BS / 64), 256, 0, stream>>>(
      nx2, W_fk, b_fk, nullptr, h_fk2, BS, DSP, DMODEL);
  gemm64_kernel<true, false><<<dim3(1, BS / 64), 256, 0, stream>>>(
      nx2, W_rk, b_rk, nullptr, h_rk2, BS, DSP, DMODEL);
  route_kernel<<<BS, 64, 0, stream>>>(h_fk2, DSP, embn + 4 * NEXP * DSP, w8 + 6 * wstr);
  bucket_kernel<<<NEXP, 64, 0, stream>>>(w8 + 6 * wstr, lists + 6 * lstr, counts + 6 * NEXP);
  route_kernel<<<BS, 64, 0, stream>>>(h_rk2, DSP, embn + 5 * NEXP * DSP, w8 + 7 * wstr);
  bucket_kernel<<<NEXP, 64, 0, stream>>>(w8 + 7 * wstr, lists + 7 * lstr, counts + 7 * NEXP);

  f2b_kernel<<<(BS * DMODEL / 4 + 255) / 256, 256, 0, stream>>>(nx2, nxb, BS * DMODEL / 4);
  wconv_kernel<<<gWF, 256, 0, stream>>>(f_kn, wbuf, DMODEL, RANK);
  expert_gemm_mfma<<<gFeat, 256, 0, stream>>>(nxb, wbuf, w8 + 6 * wstr,
                                              lists + 6 * lstr, counts + 6 * NEXP,
                                              featN, DMODEL, RANK);
  f2b_kernel<<<(BS * RANK / 4 + 255) / 256, 256, 0, stream>>>(featN, fqb, BS * RANK / 4);
  wconv_kernel<<<gWR, 256, 0, stream>>>(r_kn, wbuf, RANK, DMODEL);
  hipMemcpyAsync(d_out, x1, (size_t)BS * DMODEL * sizeof(float),
                 hipMemcpyDeviceToDevice, stream);
  expert_gemm_mfma<<<gRest, 256, 0, stream>>>(fqb, wbuf, w8 + 7 * wstr,
                                              lists + 7 * lstr, counts + 7 * NEXP,
                                              (float*)d_out, RANK, DMODEL);
}

// Round 4
// 917.037 us; speedup vs baseline: 5.4504x; 1.3171x over previous
//
#include <hip/hip_runtime.h>
#include <hip/hip_bf16.h>
#include <cstdint>

#define BS     2048   // B*S tokens
#define DMODEL 1024
#define RANK   512
#define NEXP   32
#define DSP    64
#define NHEAD  16
#define DHEAD  64
#define SEQ    1024
#define BATCH  2
#define HALL_N 384    // 6*DSP

typedef unsigned short u16;
typedef __attribute__((ext_vector_type(8))) short short8;
typedef __attribute__((ext_vector_type(4))) float f32x4;

__device__ __forceinline__ u16 bfbits(float x) {
  __hip_bfloat16 h = __float2bfloat16(x);
  return __builtin_bit_cast(u16, h);
}

__device__ __forceinline__ short8 pack8(float4 a, float4 b) {
  short8 r;
  r[0] = (short)bfbits(a.x); r[1] = (short)bfbits(a.y);
  r[2] = (short)bfbits(a.z); r[3] = (short)bfbits(a.w);
  r[4] = (short)bfbits(b.x); r[5] = (short)bfbits(b.y);
  r[6] = (short)bfbits(b.z); r[7] = (short)bfbits(b.w);
  return r;
}

// ---------------- LayerNorm (token per block, 256 thr, float4) ----------------
__global__ void ln_kernel(const float* __restrict__ x,
                          const float* __restrict__ sc,
                          const float* __restrict__ bi,
                          float* __restrict__ out) {
  int tok = blockIdx.x;
  int t = threadIdx.x; // 256
  const float4* xr = reinterpret_cast<const float4*>(x + (size_t)tok * DMODEL);
  float4 v = xr[t];
  float s = v.x + v.y + v.z + v.w;
  float q = v.x * v.x + v.y * v.y + v.z * v.z + v.w * v.w;
#pragma unroll
  for (int off = 32; off > 0; off >>= 1) {
    s += __shfl_xor(s, off);
    q += __shfl_xor(q, off);
  }
  __shared__ float red[8];
  int wid = t >> 6;
  if ((t & 63) == 0) { red[wid] = s; red[4 + wid] = q; }
  __syncthreads();
  s = red[0] + red[1] + red[2] + red[3];
  q = red[4] + red[5] + red[6] + red[7];
  float mu = s * (1.f / DMODEL);
  float var = q * (1.f / DMODEL) - mu * mu;
  float inv = rsqrtf(var + 1e-6f);
  float4 scv = reinterpret_cast<const float4*>(sc)[t];
  float4 biv = reinterpret_cast<const float4*>(bi)[t];
  float4 r;
  r.x = (v.x - mu) * inv * scv.x + biv.x;
  r.y = (v.y - mu) * inv * scv.y + biv.y;
  r.z = (v.z - mu) * inv * scv.z + biv.z;
  r.w = (v.w - mu) * inv * scv.w + biv.w;
  reinterpret_cast<float4*>(out + (size_t)tok * DMODEL)[t] = r;
}

// ---------------- emb row L2-normalize ----------------
__global__ void embnorm_kernel(const float* __restrict__ e, float* __restrict__ o) {
  int row = blockIdx.x;
  int lane = threadIdx.x; // 64
  float v = e[row * DSP + lane];
  float q = v * v;
#pragma unroll
  for (int off = 32; off > 0; off >>= 1) q += __shfl_xor(q, off);
  o[row * DSP + lane] = v / (sqrtf(q) + 1e-8f);
}

// ---------------- generic tiled GEMM (fp32): C = A[M,K]@B[K,N] (+bias) (+res) -------
template <bool BIAS, bool RES>
__global__ void gemm64_kernel(const float* __restrict__ A,
                              const float* __restrict__ Bm,
                              const float* __restrict__ bias,
                              const float* __restrict__ res,
                              float* __restrict__ C,
                              int M, int N, int K) {
  __shared__ float As[16][65];
  __shared__ float Bs[16][64];
  int n0 = blockIdx.x * 64;
  int m0 = blockIdx.y * 64;
  int t = threadIdx.x; // 256
  int tx = t & 15, ty = t >> 4;
  float c[4][4] = {};
  for (int k0 = 0; k0 < K; k0 += 16) {
#pragma unroll
    for (int i = 0; i < 4; i++) {
      int idx = t + i * 256;
      int m = idx >> 4, kk = idx & 15;
      As[kk][m] = A[(size_t)(m0 + m) * K + k0 + kk];
    }
#pragma unroll
    for (int i = 0; i < 4; i++) {
      int idx = t + i * 256;
      int kk = idx >> 6, nn = idx & 63;
      Bs[kk][nn] = Bm[(size_t)(k0 + kk) * N + n0 + nn];
    }
    __syncthreads();
#pragma unroll
    for (int kk = 0; kk < 16; kk++) {
      float a[4], b[4];
#pragma unroll
      for (int i = 0; i < 4; i++) a[i] = As[kk][ty + i * 16];
#pragma unroll
      for (int j = 0; j < 4; j++) b[j] = Bs[kk][tx + j * 16];
#pragma unroll
      for (int i = 0; i < 4; i++)
#pragma unroll
        for (int j = 0; j < 4; j++) c[i][j] += a[i] * b[j];
    }
    __syncthreads();
  }
#pragma unroll
  for (int i = 0; i < 4; i++) {
    int m = m0 + ty + i * 16;
#pragma unroll
    for (int j = 0; j < 4; j++) {
      int n = n0 + tx + j * 16;
      float v = c[i][j];
      if (BIAS) v += bias[n];
      if (RES) v += res[(size_t)m * N + n];
      C[(size_t)m * N + n] = v;
    }
  }
}

// ---------------- routing: softmax over 32 logits, top-4, renormalize ----------------
__global__ void route_kernel(const float* __restrict__ h, int ldh,
                             const float* __restrict__ e, // [32,64] normalized, pre-offset
                             float* __restrict__ wout) {  // [BS,32]
  int tok = blockIdx.x;
  int lane = threadIdx.x; // 64
  __shared__ float hs[DSP];
  __shared__ float es[NEXP * DSP];
  hs[lane] = h[(size_t)tok * ldh + lane];
#pragma unroll
  for (int i = 0; i < NEXP * DSP / 64; i++) es[lane + i * 64] = e[lane + i * 64];
  __syncthreads();
  float logit = -1e30f;
  if (lane < NEXP) {
    float s = 0.f;
#pragma unroll
    for (int d = 0; d < DSP; d++) s += hs[d] * es[lane * DSP + d];
    logit = s;
  }
  float mx = logit;
#pragma unroll
  for (int off = 16; off > 0; off >>= 1) mx = fmaxf(mx, __shfl_xor(mx, off));
  float p = (lane < NEXP) ? __expf(logit - mx) : 0.f;
  float sum = p;
#pragma unroll
  for (int off = 16; off > 0; off >>= 1) sum += __shfl_xor(sum, off);
  p = p / sum;
  float val = p;
  float chosen = 0.f;
  float selsum = 0.f;
#pragma unroll
  for (int it = 0; it < 4; it++) {
    float v = val;
    int vi = lane;
#pragma unroll
    for (int off = 16; off > 0; off >>= 1) {
      float ov = __shfl_xor(v, off);
      int oi = __shfl_xor(vi, off);
      if (ov > v || (ov == v && oi < vi)) { v = ov; vi = oi; }
    }
    if (lane == vi) { chosen = p; val = -1.f; }
    selsum += v;
  }
  if (lane < NEXP) wout[(size_t)tok * NEXP + lane] = chosen / (selsum + 1e-8f);
}

// ---------------- deterministic per-expert token list (ballot compaction) ----------------
__global__ void bucket_kernel(const float* __restrict__ w, // [BS,32]
                              int* __restrict__ list,      // [32,BS]
                              int* __restrict__ count) {   // [32]
  int n = blockIdx.x;
  int lane = threadIdx.x; // 64
  int base = 0;
  for (int t0 = 0; t0 < BS; t0 += 64) {
    int tok = t0 + lane;
    bool act = (w[(size_t)tok * NEXP + n] != 0.f);
    unsigned long long mask = __ballot(act);
    int pos = __popcll(mask & ((1ull << lane) - 1ull));
    if (act) list[n * BS + base + pos] = tok;
    base += __popcll(mask);
  }
  if (lane == 0) count[n] = base;
}

// ---------------- f32 -> bf16 elementwise (4 elems/thread) ----------------
__global__ void f2b_kernel(const float* __restrict__ in, u16* __restrict__ out, int n4) {
  int i = blockIdx.x * 256 + threadIdx.x;
  if (i >= n4) return;
  float4 v = reinterpret_cast<const float4*>(in)[i];
  ushort4 o;
  o.x = bfbits(v.x); o.y = bfbits(v.y); o.z = bfbits(v.z); o.w = bfbits(v.w);
  reinterpret_cast<ushort4*>(out)[i] = o;
}

// ---------------- weight convert+transpose: F[e][K][NOUT] f32 -> FT[e][NOUT][K] bf16 ----
__global__ void wconv_kernel(const float* __restrict__ F, u16* __restrict__ FT,
                             int K, int NOUT) {
  int e = blockIdx.z;
  int n0 = blockIdx.x * 64, k0 = blockIdx.y * 64;
  const float* Fe = F + (size_t)e * K * NOUT;
  u16* FTe = FT + (size_t)e * K * NOUT;
  __shared__ u16 tile[64][72];
  int t = threadIdx.x; // 256
  int kr = t >> 4, nc = (t & 15) * 4;
#pragma unroll
  for (int p = 0; p < 4; p++) {
    int kk = kr + p * 16;
    float4 v = *reinterpret_cast<const float4*>(Fe + (size_t)(k0 + kk) * NOUT + n0 + nc);
    tile[nc + 0][kk] = bfbits(v.x);
    tile[nc + 1][kk] = bfbits(v.y);
    tile[nc + 2][kk] = bfbits(v.z);
    tile[nc + 3][kk] = bfbits(v.w);
  }
  __syncthreads();
  int nr = t >> 2, c0 = (t & 3) * 16;
  u16* dst = FTe + (size_t)(n0 + nr) * K + k0 + c0;
  *reinterpret_cast<short8*>(dst) = *reinterpret_cast<const short8*>(&tile[nr][c0]);
  *reinterpret_cast<short8*>(dst + 8) = *reinterpret_cast<const short8*>(&tile[nr][c0 + 8]);
}

// ---------------- expert-major grouped GEMM (bf16 MFMA) ----------------
__global__ __launch_bounds__(256) void expert_gemm_mfma(
    const u16* __restrict__ Xb,   // [BS][K] bf16
    const u16* __restrict__ FT,   // [32][NOUT][K] bf16
    const float* __restrict__ w,  // [BS,32]
    const int* __restrict__ list, // [32,BS]
    const int* __restrict__ count,// [32]
    float* __restrict__ out,      // [BS,NOUT] fp32 (zeroed)
    int K, int NOUT) {
  int n = blockIdx.y;
  int cnt = count[n];
  int m0 = blockIdx.z * 64;
  if (m0 >= cnt) return;
  int n0 = blockIdx.x * 64;
  __shared__ u16 Xs[64][72];
  __shared__ u16 Fs[64][72];
  __shared__ int toks[64];
  int t = threadIdx.x;
  if (t < 64) toks[t] = (m0 + t < cnt) ? list[n * BS + m0 + t] : -1;
  __syncthreads();
  const u16* FTe = FT + ((size_t)n * NOUT + n0) * K;
  int wave = t >> 6, lane = t & 63;
  int wm = wave >> 1, wn = wave & 1;
  int lr = lane & 15, kg = lane >> 4;
  f32x4 acc[2][2] = {};
  int srow = t >> 2, sc = (t & 3) * 16;
  int tok = toks[srow];
  const u16* xrow = Xb + (size_t)(tok < 0 ? 0 : tok) * K + sc;
  const u16* frow = FTe + (size_t)srow * K + sc;
  for (int k0 = 0; k0 < K; k0 += 64) {
    short8 xv0 = {}, xv1 = {};
    if (tok >= 0) {
      xv0 = *reinterpret_cast<const short8*>(xrow + k0);
      xv1 = *reinterpret_cast<const short8*>(xrow + k0 + 8);
    }
    short8 fv0 = *reinterpret_cast<const short8*>(frow + k0);
    short8 fv1 = *reinterpret_cast<const short8*>(frow + k0 + 8);
    __syncthreads();
    *reinterpret_cast<short8*>(&Xs[srow][sc]) = xv0;
    *reinterpret_cast<short8*>(&Xs[srow][sc + 8]) = xv1;
    *reinterpret_cast<short8*>(&Fs[srow][sc]) = fv0;
    *reinterpret_cast<short8*>(&Fs[srow][sc + 8]) = fv1;
    __syncthreads();
#pragma unroll
    for (int kk = 0; kk < 2; kk++) {
      short8 a0 = *reinterpret_cast<const short8*>(&Xs[wm * 32 + lr][kk * 32 + kg * 8]);
      short8 a1 = *reinterpret_cast<const short8*>(&Xs[wm * 32 + 16 + lr][kk * 32 + kg * 8]);
      short8 b0 = *reinterpret_cast<const short8*>(&Fs[wn * 32 + lr][kk * 32 + kg * 8]);
      short8 b1 = *reinterpret_cast<const short8*>(&Fs[wn * 32 + 16 + lr][kk * 32 + kg * 8]);
      acc[0][0] = __builtin_amdgcn_mfma_f32_16x16x32_bf16(a0, b0, acc[0][0], 0, 0, 0);
      acc[0][1] = __builtin_amdgcn_mfma_f32_16x16x32_bf16(a0, b1, acc[0][1], 0, 0, 0);
      acc[1][0] = __builtin_amdgcn_mfma_f32_16x16x32_bf16(a1, b0, acc[1][0], 0, 0, 0);
      acc[1][1] = __builtin_amdgcn_mfma_f32_16x16x32_bf16(a1, b1, acc[1][1], 0, 0, 0);
    }
  }
#pragma unroll
  for (int mi = 0; mi < 2; mi++) {
#pragma unroll
    for (int j = 0; j < 4; j++) {
      int row = wm * 32 + mi * 16 + kg * 4 + j;
      int tk = toks[row];
      if (tk < 0) continue;
      float wt = w[(size_t)tk * NEXP + n];
#pragma unroll
      for (int ni = 0; ni < 2; ni++) {
        int col = n0 + wn * 32 + ni * 16 + lr;
        atomicAdd(&out[(size_t)tk * NOUT + col], wt * acc[mi][ni][j]);
      }
    }
  }
}

// ---------------- dense bf16 MFMA GEMM: C = A@B (+bias)(+res), BT = B^T [N][K] ------
template <bool BIAS, bool RES>
__global__ __launch_bounds__(256) void dense_gemm_mfma(
    const u16* __restrict__ Ab,   // [M][K] bf16
    const u16* __restrict__ BT,   // [N][K] bf16
    const float* __restrict__ bias,
    const float* __restrict__ res,
    float* __restrict__ C, int M, int N, int K) {
  int n0 = blockIdx.x * 64, m0 = blockIdx.y * 64;
  __shared__ u16 Xs[64][72];
  __shared__ u16 Fs[64][72];
  int t = threadIdx.x;
  int wave = t >> 6, lane = t & 63;
  int wm = wave >> 1, wn = wave & 1;
  int lr = lane & 15, kg = lane >> 4;
  f32x4 acc[2][2] = {};
  int srow = t >> 2, sc = (t & 3) * 16;
  const u16* xrow = Ab + (size_t)(m0 + srow) * K + sc;
  const u16* frow = BT + (size_t)(n0 + srow) * K + sc;
  for (int k0 = 0; k0 < K; k0 += 64) {
    short8 xv0 = *reinterpret_cast<const short8*>(xrow + k0);
    short8 xv1 = *reinterpret_cast<const short8*>(xrow + k0 + 8);
    short8 fv0 = *reinterpret_cast<const short8*>(frow + k0);
    short8 fv1 = *reinterpret_cast<const short8*>(frow + k0 + 8);
    __syncthreads();
    *reinterpret_cast<short8*>(&Xs[srow][sc]) = xv0;
    *reinterpret_cast<short8*>(&Xs[srow][sc + 8]) = xv1;
    *reinterpret_cast<short8*>(&Fs[srow][sc]) = fv0;
    *reinterpret_cast<short8*>(&Fs[srow][sc + 8]) = fv1;
    __syncthreads();
#pragma unroll
    for (int kk = 0; kk < 2; kk++) {
      short8 a0 = *reinterpret_cast<const short8*>(&Xs[wm * 32 + lr][kk * 32 + kg * 8]);
      short8 a1 = *reinterpret_cast<const short8*>(&Xs[wm * 32 + 16 + lr][kk * 32 + kg * 8]);
      short8 b0 = *reinterpret_cast<const short8*>(&Fs[wn * 32 + lr][kk * 32 + kg * 8]);
      short8 b1 = *reinterpret_cast<const short8*>(&Fs[wn * 32 + 16 + lr][kk * 32 + kg * 8]);
      acc[0][0] = __builtin_amdgcn_mfma_f32_16x16x32_bf16(a0, b0, acc[0][0], 0, 0, 0);
      acc[0][1] = __builtin_amdgcn_mfma_f32_16x16x32_bf16(a0, b1, acc[0][1], 0, 0, 0);
      acc[1][0] = __builtin_amdgcn_mfma_f32_16x16x32_bf16(a1, b0, acc[1][0], 0, 0, 0);
      acc[1][1] = __builtin_amdgcn_mfma_f32_16x16x32_bf16(a1, b1, acc[1][1], 0, 0, 0);
    }
  }
#pragma unroll
  for (int mi = 0; mi < 2; mi++) {
#pragma unroll
    for (int j = 0; j < 4; j++) {
      int row = m0 + wm * 32 + mi * 16 + kg * 4 + j;
#pragma unroll
      for (int ni = 0; ni < 2; ni++) {
        int col = n0 + wn * 32 + ni * 16 + lr;
        float v = acc[mi][ni][j];
        if (BIAS) v += bias[col];
        if (RES) v += res[(size_t)row * N + col];
        C[(size_t)row * N + col] = v;
      }
    }
  }
}

// ---------------- causal flash attention (bf16 MFMA) ----------------
// grid (SEQ/64 reversed, NHEAD, BATCH), 256 thr. Wave owns 16 q-rows.
__global__ __launch_bounds__(256) void attn_mfma(const float* __restrict__ Qb,
                                                 const float* __restrict__ Kb,
                                                 const float* __restrict__ Vb,
                                                 u16* __restrict__ Ob) {
  int qt = (gridDim.x - 1 - blockIdx.x) * 64;  // long blocks first
  int h = blockIdx.y, b = blockIdx.z;
  int t = threadIdx.x;
  int w = t >> 6, lane = t & 63;
  int lr = lane & 15, kg = lane >> 4;
  __shared__ u16 Ks[64][72];
  __shared__ u16 Vs[64][66];   // transposed: [d][key], pitch 66 -> conflict-free
  __shared__ u16 Ps[4][16][72];
  size_t base = (size_t)(b * SEQ) * DMODEL + (size_t)h * DHEAD;
  // Q A-frags (rows w*16+lr), pre-scaled by 1/sqrt(64)
  short8 aq0, aq1;
  {
    const float* qrow = Qb + base + (size_t)(qt + w * 16 + lr) * DMODEL + kg * 8;
    float4 v0 = *reinterpret_cast<const float4*>(qrow);
    float4 v1 = *reinterpret_cast<const float4*>(qrow + 4);
    float4 v2 = *reinterpret_cast<const float4*>(qrow + 32);
    float4 v3 = *reinterpret_cast<const float4*>(qrow + 36);
    const float sc = 0.125f;
    v0.x *= sc; v0.y *= sc; v0.z *= sc; v0.w *= sc;
    v1.x *= sc; v1.y *= sc; v1.z *= sc; v1.w *= sc;
    v2.x *= sc; v2.y *= sc; v2.z *= sc; v2.w *= sc;
    v3.x *= sc; v3.y *= sc; v3.z *= sc; v3.w *= sc;
    aq0 = pack8(v0, v1);
    aq1 = pack8(v2, v3);
  }
  float m[4], l[4];
#pragma unroll
  for (int j = 0; j < 4; j++) { m[j] = -1e30f; l[j] = 0.f; }
  f32x4 acc_o[4] = {};
  for (int kt = 0; kt <= qt; kt += 64) {
    __syncthreads();
    {
      // K tile: row-major bf16
      int r = t >> 2, c0 = (t & 3) * 16;
      const float* krow = Kb + base + (size_t)(kt + r) * DMODEL + c0;
      float4 k0 = *reinterpret_cast<const float4*>(krow);
      float4 k1 = *reinterpret_cast<const float4*>(krow + 4);
      float4 k2 = *reinterpret_cast<const float4*>(krow + 8);
      float4 k3 = *reinterpret_cast<const float4*>(krow + 12);
      *reinterpret_cast<short8*>(&Ks[r][c0]) = pack8(k0, k1);
      *reinterpret_cast<short8*>(&Ks[r][c0 + 8]) = pack8(k2, k3);
      // V tile transposed: lane owns dim d=lane, wave owns 16 keys
      int d = lane;
      int r0v = w * 16;
      const float* vcol = Vb + base + (size_t)(kt + r0v) * DMODEL + d;
#pragma unroll
      for (int i = 0; i < 16; i++)
        Vs[d][r0v + i] = bfbits(vcol[(size_t)i * DMODEL]);
    }
    __syncthreads();
    // S = Q K^T : 4 col-tiles x 2 k-chunks
    f32x4 s[4] = {};
#pragma unroll
    for (int c = 0; c < 4; c++) {
      short8 bk0 = *reinterpret_cast<const short8*>(&Ks[c * 16 + lr][kg * 8]);
      short8 bk1 = *reinterpret_cast<const short8*>(&Ks[c * 16 + lr][32 + kg * 8]);
      s[c] = __builtin_amdgcn_mfma_f32_16x16x32_bf16(aq0, bk0, s[c], 0, 0, 0);
      s[c] = __builtin_amdgcn_mfma_f32_16x16x32_bf16(aq1, bk1, s[c], 0, 0, 0);
    }
    if (kt == qt) {  // diagonal tile: causal mask (local indices)
#pragma unroll
      for (int c = 0; c < 4; c++)
#pragma unroll
        for (int j = 0; j < 4; j++)
          if (c * 16 + lr > w * 16 + kg * 4 + j) s[c][j] = -1e30f;
    }
    // row max across in-lane tiles + 16-lane group
    float mt[4];
#pragma unroll
    for (int j = 0; j < 4; j++)
      mt[j] = fmaxf(fmaxf(s[0][j], s[1][j]), fmaxf(s[2][j], s[3][j]));
#pragma unroll
    for (int off = 1; off < 16; off <<= 1)
#pragma unroll
      for (int j = 0; j < 4; j++) mt[j] = fmaxf(mt[j], __shfl_xor(mt[j], off));
    float corr[4];
#pragma unroll
    for (int j = 0; j < 4; j++) {
      float mn = fmaxf(m[j], mt[j]);
      corr[j] = __expf(m[j] - mn);
      m[j] = mn;
      l[j] *= corr[j];
    }
#pragma unroll
    for (int di = 0; di < 4; di++)
#pragma unroll
      for (int j = 0; j < 4; j++) acc_o[di][j] *= corr[j];
    // P = exp(S-m), row sums
    float ps[4] = {0.f, 0.f, 0.f, 0.f};
#pragma unroll
    for (int c = 0; c < 4; c++)
#pragma unroll
      for (int j = 0; j < 4; j++) {
        float p = __expf(s[c][j] - m[j]);
        ps[j] += p;
        s[c][j] = p;
      }
#pragma unroll
    for (int off = 1; off < 16; off <<= 1)
#pragma unroll
      for (int j = 0; j < 4; j++) ps[j] += __shfl_xor(ps[j], off);
#pragma unroll
    for (int j = 0; j < 4; j++) l[j] += ps[j];
    // P -> LDS (per-wave region; same-wave dependency, no barrier)
#pragma unroll
    for (int c = 0; c < 4; c++)
#pragma unroll
      for (int j = 0; j < 4; j++)
        Ps[w][kg * 4 + j][c * 16 + lr] = bfbits(s[c][j]);
    short8 pa0 = *reinterpret_cast<const short8*>(&Ps[w][lr][kg * 8]);
    short8 pa1 = *reinterpret_cast<const short8*>(&Ps[w][lr][32 + kg * 8]);
    // O += P V
#pragma unroll
    for (int di = 0; di < 4; di++) {
      short8 bv0 = *reinterpret_cast<const short8*>(&Vs[di * 16 + lr][kg * 8]);
      short8 bv1 = *reinterpret_cast<const short8*>(&Vs[di * 16 + lr][32 + kg * 8]);
      acc_o[di] = __builtin_amdgcn_mfma_f32_16x16x32_bf16(pa0, bv0, acc_o[di], 0, 0, 0);
      acc_o[di] = __builtin_amdgcn_mfma_f32_16x16x32_bf16(pa1, bv1, acc_o[di], 0, 0, 0);
    }
  }
#pragma unroll
  for (int j = 0; j < 4; j++) {
    float inv = 1.f / l[j];
    size_t rowoff = base + (size_t)(qt + w * 16 + kg * 4 + j) * DMODEL;
#pragma unroll
    for (int di = 0; di < 4; di++)
      Ob[rowoff + di * 16 + lr] = bfbits(acc_o[di][j] * inv);
  }
}

// ---------------- launch ----------------
extern "C" void kernel_launch(void* const* d_in, const int* in_sizes, int n_in,
                              void* d_out, int out_size, void* d_ws, size_t ws_size,
                              hipStream_t stream) {
  const float* x    = (const float*)d_in[0];
  const float* f_qk = (const float*)d_in[1];
  const float* f_v  = (const float*)d_in[2];
  const float* r_qk = (const float*)d_in[3];
  const float* r_v  = (const float*)d_in[4];
  const float* f_kn = (const float*)d_in[5];
  const float* r_kn = (const float*)d_in[6];
  const float* nemb = (const float*)d_in[7];
  const float* W_all = (const float*)d_in[8];
  const float* b_all = (const float*)d_in[9];
  const float* W_fk  = (const float*)d_in[10];
  const float* b_fk  = (const float*)d_in[11];
  const float* W_rk  = (const float*)d_in[12];
  const float* b_rk  = (const float*)d_in[13];
  const float* W_o   = (const float*)d_in[14];
  const float* ln1s  = (const float*)d_in[15];
  const float* ln1b  = (const float*)d_in[16];
  const float* ln2s  = (const float*)d_in[17];
  const float* ln2b  = (const float*)d_in[18];

  float* ws = (float*)d_ws;
  size_t off = 0;
  auto alloc = [&](size_t nf) { float* p = ws + off; off += nf; return p; };
  float* nx    = alloc((size_t)BS * DMODEL);
  float* nx2   = alloc((size_t)BS * DMODEL);
  float* embn  = alloc(6 * NEXP * DSP);
  float* h_all = alloc((size_t)BS * HALL_N);
  float* h_fk2 = alloc((size_t)BS * DSP);
  float* h_rk2 = alloc((size_t)BS * DSP);
  float* w8    = alloc((size_t)8 * BS * NEXP);
  float* featQ = alloc((size_t)BS * RANK);   // ---- zeroed region start
  float* featK = alloc((size_t)BS * RANK);
  float* featV = alloc((size_t)BS * RANK);
  float* featN = alloc((size_t)BS * RANK);
  float* Qb    = alloc((size_t)BS * DMODEL);
  float* Kb    = alloc((size_t)BS * DMODEL);
  float* Vb    = alloc((size_t)BS * DMODEL); // ---- zeroed region end
  float* scratch = alloc((size_t)BS * DMODEL);  // carved: attnOb / woT (u16)
  float* x1    = alloc((size_t)BS * DMODEL);
  int* lists   = (int*)(ws + off); off += (size_t)8 * NEXP * BS;
  int* counts  = (int*)(ws + off); off += 8 * NEXP;
  u16* nxb  = (u16*)(ws + off); off += (size_t)BS * DMODEL / 2;
  u16* fqb  = (u16*)(ws + off); off += (size_t)BS * RANK / 2;
  u16* fkb  = (u16*)(ws + off); off += (size_t)BS * RANK / 2;
  u16* fvb  = (u16*)(ws + off); off += (size_t)BS * RANK / 2;
  u16* wbuf = (u16*)(ws + off); off += (size_t)NEXP * DMODEL * RANK / 2;
  // carve bf16 attn output + W_o^T from scratch (8.4 MB >= 4.2 + 2.1 MB)
  u16* attnOb = (u16*)scratch;
  u16* woT    = attnOb + (size_t)BS * DMODEL;

  const size_t wstr = (size_t)BS * NEXP;
  const size_t lstr = (size_t)NEXP * BS;

  embnorm_kernel<<<6 * NEXP, DSP, 0, stream>>>(nemb, embn);
  wconv_kernel<<<dim3(DMODEL / 64, DMODEL / 64, 1), 256, 0, stream>>>(W_o, woT, DMODEL, DMODEL);
  ln_kernel<<<BS, 256, 0, stream>>>(x, ln1s, ln1b, nx);
  gemm64_kernel<true, false><<<dim3(HALL_N / 64, BS / 64), 256, 0, stream>>>(
      nx, W_all, b_all, nullptr, h_all, BS, HALL_N, DMODEL);

  size_t zero_flts = (size_t)4 * BS * RANK + (size_t)3 * BS * DMODEL;
  hipMemsetAsync(featQ, 0, zero_flts * sizeof(float), stream);

  const int poolOf[8] = {0, 0, 1, 2, 2, 3, 4, 5};
  for (int r = 0; r < 6; r++) {
    route_kernel<<<BS, 64, 0, stream>>>(h_all + r * DSP, HALL_N,
                                        embn + poolOf[r] * NEXP * DSP,
                                        w8 + r * wstr);
    bucket_kernel<<<NEXP, 64, 0, stream>>>(w8 + r * wstr, lists + r * lstr,
                                           counts + r * NEXP);
  }

  f2b_kernel<<<(BS * DMODEL / 4 + 255) / 256, 256, 0, stream>>>(nx, nxb, BS * DMODEL / 4);

  dim3 gFeat(RANK / 64, NEXP, BS / 64);
  dim3 gRest(DMODEL / 64, NEXP, BS / 64);
  dim3 gWF(RANK / 64, DMODEL / 64, NEXP);
  dim3 gWR(DMODEL / 64, RANK / 64, NEXP);

  // features (K=1024 -> R=512)
  wconv_kernel<<<gWF, 256, 0, stream>>>(f_qk, wbuf, DMODEL, RANK);
  expert_gemm_mfma<<<gFeat, 256, 0, stream>>>(nxb, wbuf, w8 + 0 * wstr,
                                              lists + 0 * lstr, counts + 0 * NEXP,
                                              featQ, DMODEL, RANK);
  expert_gemm_mfma<<<gFeat, 256, 0, stream>>>(nxb, wbuf, w8 + 1 * wstr,
                                              lists + 1 * lstr, counts + 1 * NEXP,
                                              featK, DMODEL, RANK);
  wconv_kernel<<<gWF, 256, 0, stream>>>(f_v, wbuf, DMODEL, RANK);
  expert_gemm_mfma<<<gFeat, 256, 0, stream>>>(nxb, wbuf, w8 + 2 * wstr,
                                              lists + 2 * lstr, counts + 2 * NEXP,
                                              featV, DMODEL, RANK);
  f2b_kernel<<<(BS * RANK / 4 + 255) / 256, 256, 0, stream>>>(featQ, fqb, BS * RANK / 4);
  f2b_kernel<<<(BS * RANK / 4 + 255) / 256, 256, 0, stream>>>(featK, fkb, BS * RANK / 4);
  f2b_kernel<<<(BS * RANK / 4 + 255) / 256, 256, 0, stream>>>(featV, fvb, BS * RANK / 4);
  // restores (K=512 -> D=1024)
  wconv_kernel<<<gWR, 256, 0, stream>>>(r_qk, wbuf, RANK, DMODEL);
  expert_gemm_mfma<<<gRest, 256, 0, stream>>>(fqb, wbuf, w8 + 3 * wstr,
                                              lists + 3 * lstr, counts + 3 * NEXP,
                                              Qb, RANK, DMODEL);
  expert_gemm_mfma<<<gRest, 256, 0, stream>>>(fkb, wbuf, w8 + 4 * wstr,
                                              lists + 4 * lstr, counts + 4 * NEXP,
                                              Kb, RANK, DMODEL);
  wconv_kernel<<<gWR, 256, 0, stream>>>(r_v, wbuf, RANK, DMODEL);
  expert_gemm_mfma<<<gRest, 256, 0, stream>>>(fvb, wbuf, w8 + 5 * wstr,
                                              lists + 5 * lstr, counts + 5 * NEXP,
                                              Vb, RANK, DMODEL);

  attn_mfma<<<dim3(SEQ / 64, NHEAD, BATCH), 256, 0, stream>>>(Qb, Kb, Vb, attnOb);

  // x1 = x + attnO @ W_o   (bf16 MFMA)
  dense_gemm_mfma<false, true><<<dim3(DMODEL / 64, BS / 64), 256, 0, stream>>>(
      attnOb, woT, nullptr, x, x1, BS, DMODEL, DMODEL);

  // knowledge circuit
  ln_kernel<<<BS, 256, 0, stream>>>(x1, ln2s, ln2b, nx2);
  gemm64_kernel<true, false><<<dim3(1, BS / 64), 256, 0, stream>>>(
      nx2, W_fk, b_fk, nullptr, h_fk2, BS, DSP, DMODEL);
  gemm64_kernel<true, false><<<dim3(1, BS / 64), 256, 0, stream>>>(
      nx2, W_rk, b_rk, nullptr, h_rk2, BS, DSP, DMODEL);
  route_kernel<<<BS, 64, 0, stream>>>(h_fk2, DSP, embn + 4 * NEXP * DSP, w8 + 6 * wstr);
  bucket_kernel<<<NEXP, 64, 0, stream>>>(w8 + 6 * wstr, lists + 6 * lstr, counts + 6 * NEXP);
  route_kernel<<<BS, 64, 0, stream>>>(h_rk2, DSP, embn + 5 * NEXP * DSP, w8 + 7 * wstr);
  bucket_kernel<<<NEXP, 64, 0, stream>>>(w8 + 7 * wstr, lists + 7 * lstr, counts + 7 * NEXP);

  f2b_kernel<<<(BS * DMODEL / 4 + 255) / 256, 256, 0, stream>>>(nx2, nxb, BS * DMODEL / 4);
  wconv_kernel<<<gWF, 256, 0, stream>>>(f_kn, wbuf, DMODEL, RANK);
  expert_gemm_mfma<<<gFeat, 256, 0, stream>>>(nxb, wbuf, w8 + 6 * wstr,
                                              lists + 6 * lstr, counts + 6 * NEXP,
                                              featN, DMODEL, RANK);
  f2b_kernel<<<(BS * RANK / 4 + 255) / 256, 256, 0, stream>>>(featN, fqb, BS * RANK / 4);
  wconv_kernel<<<gWR, 256, 0, stream>>>(r_kn, wbuf, RANK, DMODEL);
  hipMemcpyAsync(d_out, x1, (size_t)BS * DMODEL * sizeof(float),
                 hipMemcpyDeviceToDevice, stream);
  expert_gemm_mfma<<<gRest, 256, 0, stream>>>(fqb, wbuf, w8 + 7 * wstr,
                                              lists + 7 * lstr, counts + 7 * NEXP,
                                              (float*)d_out, RANK, DMODEL);
}

// Round 5
// 736.962 us; speedup vs baseline: 6.7822x; 1.2443x over previous
//
#include <hip/hip_runtime.h>
#include <hip/hip_bf16.h>
#include <cstdint>

#define BS     2048   // B*S tokens
#define DMODEL 1024
#define RANK   512
#define NEXP   32
#define DSP    64
#define NHEAD  16
#define DHEAD  64
#define SEQ    1024
#define BATCH  2
#define HALL_N 384    // 6*DSP

typedef unsigned short u16;
typedef __attribute__((ext_vector_type(8))) short short8;
typedef __attribute__((ext_vector_type(4))) float f32x4;

__device__ __forceinline__ u16 bfbits(float x) {
  __hip_bfloat16 h = __float2bfloat16(x);
  return __builtin_bit_cast(u16, h);
}

__device__ __forceinline__ short8 pack8(float4 a, float4 b) {
  short8 r;
  r[0] = (short)bfbits(a.x); r[1] = (short)bfbits(a.y);
  r[2] = (short)bfbits(a.z); r[3] = (short)bfbits(a.w);
  r[4] = (short)bfbits(b.x); r[5] = (short)bfbits(b.y);
  r[6] = (short)bfbits(b.z); r[7] = (short)bfbits(b.w);
  return r;
}

// ---------------- LayerNorm (token per block, 256 thr, float4), fp32 + bf16 out ----
__global__ void ln_kernel(const float* __restrict__ x,
                          const float* __restrict__ sc,
                          const float* __restrict__ bi,
                          float* __restrict__ out,
                          u16* __restrict__ outb) {
  int tok = blockIdx.x;
  int t = threadIdx.x; // 256
  const float4* xr = reinterpret_cast<const float4*>(x + (size_t)tok * DMODEL);
  float4 v = xr[t];
  float s = v.x + v.y + v.z + v.w;
  float q = v.x * v.x + v.y * v.y + v.z * v.z + v.w * v.w;
#pragma unroll
  for (int off = 32; off > 0; off >>= 1) {
    s += __shfl_xor(s, off);
    q += __shfl_xor(q, off);
  }
  __shared__ float red[8];
  int wid = t >> 6;
  if ((t & 63) == 0) { red[wid] = s; red[4 + wid] = q; }
  __syncthreads();
  s = red[0] + red[1] + red[2] + red[3];
  q = red[4] + red[5] + red[6] + red[7];
  float mu = s * (1.f / DMODEL);
  float var = q * (1.f / DMODEL) - mu * mu;
  float inv = rsqrtf(var + 1e-6f);
  float4 scv = reinterpret_cast<const float4*>(sc)[t];
  float4 biv = reinterpret_cast<const float4*>(bi)[t];
  float4 r;
  r.x = (v.x - mu) * inv * scv.x + biv.x;
  r.y = (v.y - mu) * inv * scv.y + biv.y;
  r.z = (v.z - mu) * inv * scv.z + biv.z;
  r.w = (v.w - mu) * inv * scv.w + biv.w;
  reinterpret_cast<float4*>(out + (size_t)tok * DMODEL)[t] = r;
  ushort4 ob;
  ob.x = bfbits(r.x); ob.y = bfbits(r.y); ob.z = bfbits(r.z); ob.w = bfbits(r.w);
  reinterpret_cast<ushort4*>(outb + (size_t)tok * DMODEL)[t] = ob;
}

// ---------------- emb row L2-normalize ----------------
__global__ void embnorm_kernel(const float* __restrict__ e, float* __restrict__ o) {
  int row = blockIdx.x;
  int lane = threadIdx.x; // 64
  float v = e[row * DSP + lane];
  float q = v * v;
#pragma unroll
  for (int off = 32; off > 0; off >>= 1) q += __shfl_xor(q, off);
  o[row * DSP + lane] = v / (sqrtf(q) + 1e-8f);
}

// ---------------- fp32 split-K GEMM: part[ks] = A[M,Kc]@B[Kc,N] ----------------
__global__ __launch_bounds__(256) void gemm_splitk(const float* __restrict__ A,
                                                   const float* __restrict__ Bm,
                                                   float* __restrict__ part,
                                                   int M, int N, int K, int kchunk) {
  __shared__ float As[16][65];
  __shared__ float Bs[16][64];
  int n0 = blockIdx.x * 64;
  int m0 = blockIdx.y * 64;
  int kbeg = blockIdx.z * kchunk;
  int t = threadIdx.x;
  int tx = t & 15, ty = t >> 4;
  float c[4][4] = {};
  for (int k0 = kbeg; k0 < kbeg + kchunk; k0 += 16) {
#pragma unroll
    for (int i = 0; i < 4; i++) {
      int idx = t + i * 256;
      int m = idx >> 4, kk = idx & 15;
      As[kk][m] = A[(size_t)(m0 + m) * K + k0 + kk];
    }
#pragma unroll
    for (int i = 0; i < 4; i++) {
      int idx = t + i * 256;
      int kk = idx >> 6, nn = idx & 63;
      Bs[kk][nn] = Bm[(size_t)(k0 + kk) * N + n0 + nn];
    }
    __syncthreads();
#pragma unroll
    for (int kk = 0; kk < 16; kk++) {
      float a[4], b[4];
#pragma unroll
      for (int i = 0; i < 4; i++) a[i] = As[kk][ty + i * 16];
#pragma unroll
      for (int j = 0; j < 4; j++) b[j] = Bs[kk][tx + j * 16];
#pragma unroll
      for (int i = 0; i < 4; i++)
#pragma unroll
        for (int j = 0; j < 4; j++) c[i][j] += a[i] * b[j];
    }
    __syncthreads();
  }
  float* po = part + (size_t)blockIdx.z * M * N;
#pragma unroll
  for (int i = 0; i < 4; i++)
#pragma unroll
    for (int j = 0; j < 4; j++)
      po[(size_t)(m0 + ty + i * 16) * N + n0 + tx + j * 16] = c[i][j];
}

// ---------------- split-K reduce + bias ----------------
__global__ void reduce_bias_kernel(const float* __restrict__ part,
                                   const float* __restrict__ bias,
                                   float* __restrict__ out,
                                   int MN, int N, int KS) {
  int i = blockIdx.x * 256 + threadIdx.x;
  if (i * 4 >= MN) return;
  float4 s = reinterpret_cast<const float4*>(part)[i];
  for (int ks = 1; ks < KS; ks++) {
    float4 p = reinterpret_cast<const float4*>(part + (size_t)ks * MN)[i];
    s.x += p.x; s.y += p.y; s.z += p.z; s.w += p.w;
  }
  int col = (i * 4) % N;
  float4 b = *reinterpret_cast<const float4*>(bias + col);
  s.x += b.x; s.y += b.y; s.z += b.z; s.w += b.w;
  reinterpret_cast<float4*>(out)[i] = s;
}

// ---------------- routing: softmax over 32 logits, top-4, renormalize ----------------
__global__ void route_kernel(const float* __restrict__ h, int ldh,
                             const float* __restrict__ e, // [32,64] normalized, pre-offset
                             float* __restrict__ wout) {  // [BS,32]
  int tok = blockIdx.x;
  int lane = threadIdx.x; // 64
  __shared__ float hs[DSP];
  __shared__ float es[NEXP * DSP];
  hs[lane] = h[(size_t)tok * ldh + lane];
#pragma unroll
  for (int i = 0; i < NEXP * DSP / 64; i++) es[lane + i * 64] = e[lane + i * 64];
  __syncthreads();
  float logit = -1e30f;
  if (lane < NEXP) {
    float s = 0.f;
#pragma unroll
    for (int d = 0; d < DSP; d++) s += hs[d] * es[lane * DSP + d];
    logit = s;
  }
  float mx = logit;
#pragma unroll
  for (int off = 16; off > 0; off >>= 1) mx = fmaxf(mx, __shfl_xor(mx, off));
  float p = (lane < NEXP) ? __expf(logit - mx) : 0.f;
  float sum = p;
#pragma unroll
  for (int off = 16; off > 0; off >>= 1) sum += __shfl_xor(sum, off);
  p = p / sum;
  float val = p;
  float chosen = 0.f;
  float selsum = 0.f;
#pragma unroll
  for (int it = 0; it < 4; it++) {
    float v = val;
    int vi = lane;
#pragma unroll
    for (int off = 16; off > 0; off >>= 1) {
      float ov = __shfl_xor(v, off);
      int oi = __shfl_xor(vi, off);
      if (ov > v || (ov == v && oi < vi)) { v = ov; vi = oi; }
    }
    if (lane == vi) { chosen = p; val = -1.f; }
    selsum += v;
  }
  if (lane < NEXP) wout[(size_t)tok * NEXP + lane] = chosen / (selsum + 1e-8f);
}

// ---------------- deterministic per-expert token list (ballot compaction) ----------------
__global__ void bucket_kernel(const float* __restrict__ w, // [BS,32]
                              int* __restrict__ list,      // [32,BS]
                              int* __restrict__ count) {   // [32]
  int n = blockIdx.x;
  int lane = threadIdx.x; // 64
  int base = 0;
  for (int t0 = 0; t0 < BS; t0 += 64) {
    int tok = t0 + lane;
    bool act = (w[(size_t)tok * NEXP + n] != 0.f);
    unsigned long long mask = __ballot(act);
    int pos = __popcll(mask & ((1ull << lane) - 1ull));
    if (act) list[n * BS + base + pos] = tok;
    base += __popcll(mask);
  }
  if (lane == 0) count[n] = base;
}

// ---------------- f32 -> bf16 elementwise (4 elems/thread) ----------------
__global__ void f2b_kernel(const float* __restrict__ in, u16* __restrict__ out, int n4) {
  int i = blockIdx.x * 256 + threadIdx.x;
  if (i >= n4) return;
  float4 v = reinterpret_cast<const float4*>(in)[i];
  ushort4 o;
  o.x = bfbits(v.x); o.y = bfbits(v.y); o.z = bfbits(v.z); o.w = bfbits(v.w);
  reinterpret_cast<ushort4*>(out)[i] = o;
}

// ---------------- weight convert+transpose: F[e][K][NOUT] f32 -> FT[e][NOUT][K] bf16 ----
__global__ void wconv_kernel(const float* __restrict__ F, u16* __restrict__ FT,
                             int K, int NOUT) {
  int e = blockIdx.z;
  int n0 = blockIdx.x * 64, k0 = blockIdx.y * 64;
  const float* Fe = F + (size_t)e * K * NOUT;
  u16* FTe = FT + (size_t)e * K * NOUT;
  __shared__ u16 tile[64][72];
  int t = threadIdx.x; // 256
  int kr = t >> 4, nc = (t & 15) * 4;
#pragma unroll
  for (int p = 0; p < 4; p++) {
    int kk = kr + p * 16;
    float4 v = *reinterpret_cast<const float4*>(Fe + (size_t)(k0 + kk) * NOUT + n0 + nc);
    tile[nc + 0][kk] = bfbits(v.x);
    tile[nc + 1][kk] = bfbits(v.y);
    tile[nc + 2][kk] = bfbits(v.z);
    tile[nc + 3][kk] = bfbits(v.w);
  }
  __syncthreads();
  int nr = t >> 2, c0 = (t & 3) * 16;
  u16* dst = FTe + (size_t)(n0 + nr) * K + k0 + c0;
  *reinterpret_cast<short8*>(dst) = *reinterpret_cast<const short8*>(&tile[nr][c0]);
  *reinterpret_cast<short8*>(dst + 8) = *reinterpret_cast<const short8*>(&tile[nr][c0 + 8]);
}

// ---------------- expert-major grouped GEMM (bf16 MFMA, 128x64 tile) ----------------
// out[t,:] += w[t,n] * Xb[t,:] @ F[n]  with FT[n] = F[n]^T ([NOUT][K], k-contiguous)
__global__ __launch_bounds__(256) void expert_gemm_mfma(
    const u16* __restrict__ Xb,   // [BS][K] bf16
    const u16* __restrict__ FT,   // [32][NOUT][K] bf16
    const float* __restrict__ w,  // [BS,32]
    const int* __restrict__ list, // [32,BS]
    const int* __restrict__ count,// [32]
    float* __restrict__ out,      // [BS,NOUT] fp32 (zeroed)
    int K, int NOUT) {
  int n = blockIdx.y;
  int cnt = count[n];
  int m0 = blockIdx.z * 128;
  if (m0 >= cnt) return;
  int n0 = blockIdx.x * 64;
  __shared__ u16 Xs[128][72];
  __shared__ u16 Fs[64][72];
  __shared__ int toks[128];
  int t = threadIdx.x;
  if (t < 128) toks[t] = (m0 + t < cnt) ? list[n * BS + m0 + t] : -1;
  __syncthreads();
  const u16* FTe = FT + ((size_t)n * NOUT + n0) * K;
  int wave = t >> 6, lane = t & 63;
  int wm = wave >> 1, wn = wave & 1;
  int lr = lane & 15, kg = lane >> 4;
  f32x4 acc[4][2] = {};
  // staging coords: X row per 2 threads (32 u16 each half), F row per 4 threads
  int xri = t >> 1, xc = (t & 1) * 32;
  int tokr = toks[xri];
  const u16* xrow = Xb + (size_t)(tokr < 0 ? 0 : tokr) * K + xc;
  int fri = t >> 2, fc = (t & 3) * 16;
  const u16* frow = FTe + (size_t)fri * K + fc;
  for (int k0 = 0; k0 < K; k0 += 64) {
    short8 xv0 = {}, xv1 = {}, xv2 = {}, xv3 = {};
    if (tokr >= 0) {
      xv0 = *reinterpret_cast<const short8*>(xrow + k0);
      xv1 = *reinterpret_cast<const short8*>(xrow + k0 + 8);
      xv2 = *reinterpret_cast<const short8*>(xrow + k0 + 16);
      xv3 = *reinterpret_cast<const short8*>(xrow + k0 + 24);
    }
    short8 fv0 = *reinterpret_cast<const short8*>(frow + k0);
    short8 fv1 = *reinterpret_cast<const short8*>(frow + k0 + 8);
    __syncthreads();
    *reinterpret_cast<short8*>(&Xs[xri][xc]) = xv0;
    *reinterpret_cast<short8*>(&Xs[xri][xc + 8]) = xv1;
    *reinterpret_cast<short8*>(&Xs[xri][xc + 16]) = xv2;
    *reinterpret_cast<short8*>(&Xs[xri][xc + 24]) = xv3;
    *reinterpret_cast<short8*>(&Fs[fri][fc]) = fv0;
    *reinterpret_cast<short8*>(&Fs[fri][fc + 8]) = fv1;
    __syncthreads();
#pragma unroll
    for (int kk = 0; kk < 2; kk++) {
      short8 b0 = *reinterpret_cast<const short8*>(&Fs[wn * 32 + lr][kk * 32 + kg * 8]);
      short8 b1 = *reinterpret_cast<const short8*>(&Fs[wn * 32 + 16 + lr][kk * 32 + kg * 8]);
#pragma unroll
      for (int mi = 0; mi < 4; mi++) {
        short8 a = *reinterpret_cast<const short8*>(&Xs[wm * 64 + mi * 16 + lr][kk * 32 + kg * 8]);
        acc[mi][0] = __builtin_amdgcn_mfma_f32_16x16x32_bf16(a, b0, acc[mi][0], 0, 0, 0);
        acc[mi][1] = __builtin_amdgcn_mfma_f32_16x16x32_bf16(a, b1, acc[mi][1], 0, 0, 0);
      }
    }
  }
#pragma unroll
  for (int mi = 0; mi < 4; mi++) {
#pragma unroll
    for (int j = 0; j < 4; j++) {
      int row = wm * 64 + mi * 16 + kg * 4 + j;
      int tk = toks[row];
      if (tk < 0) continue;
      float wt = w[(size_t)tk * NEXP + n];
#pragma unroll
      for (int ni = 0; ni < 2; ni++) {
        int col = n0 + wn * 32 + ni * 16 + lr;
        atomicAdd(&out[(size_t)tk * NOUT + col], wt * acc[mi][ni][j]);
      }
    }
  }
}

// ---------------- dense bf16 MFMA GEMM: C = A@B (+bias)(+res), BT = B^T [N][K] ------
template <bool BIAS, bool RES>
__global__ __launch_bounds__(256) void dense_gemm_mfma(
    const u16* __restrict__ Ab,   // [M][K] bf16
    const u16* __restrict__ BT,   // [N][K] bf16
    const float* __restrict__ bias,
    const float* __restrict__ res,
    float* __restrict__ C, int M, int N, int K) {
  int n0 = blockIdx.x * 64, m0 = blockIdx.y * 64;
  __shared__ u16 Xs[64][72];
  __shared__ u16 Fs[64][72];
  int t = threadIdx.x;
  int wave = t >> 6, lane = t & 63;
  int wm = wave >> 1, wn = wave & 1;
  int lr = lane & 15, kg = lane >> 4;
  f32x4 acc[2][2] = {};
  int srow = t >> 2, sc = (t & 3) * 16;
  const u16* xrow = Ab + (size_t)(m0 + srow) * K + sc;
  const u16* frow = BT + (size_t)(n0 + srow) * K + sc;
  for (int k0 = 0; k0 < K; k0 += 64) {
    short8 xv0 = *reinterpret_cast<const short8*>(xrow + k0);
    short8 xv1 = *reinterpret_cast<const short8*>(xrow + k0 + 8);
    short8 fv0 = *reinterpret_cast<const short8*>(frow + k0);
    short8 fv1 = *reinterpret_cast<const short8*>(frow + k0 + 8);
    __syncthreads();
    *reinterpret_cast<short8*>(&Xs[srow][sc]) = xv0;
    *reinterpret_cast<short8*>(&Xs[srow][sc + 8]) = xv1;
    *reinterpret_cast<short8*>(&Fs[srow][sc]) = fv0;
    *reinterpret_cast<short8*>(&Fs[srow][sc + 8]) = fv1;
    __syncthreads();
#pragma unroll
    for (int kk = 0; kk < 2; kk++) {
      short8 a0 = *reinterpret_cast<const short8*>(&Xs[wm * 32 + lr][kk * 32 + kg * 8]);
      short8 a1 = *reinterpret_cast<const short8*>(&Xs[wm * 32 + 16 + lr][kk * 32 + kg * 8]);
      short8 b0 = *reinterpret_cast<const short8*>(&Fs[wn * 32 + lr][kk * 32 + kg * 8]);
      short8 b1 = *reinterpret_cast<const short8*>(&Fs[wn * 32 + 16 + lr][kk * 32 + kg * 8]);
      acc[0][0] = __builtin_amdgcn_mfma_f32_16x16x32_bf16(a0, b0, acc[0][0], 0, 0, 0);
      acc[0][1] = __builtin_amdgcn_mfma_f32_16x16x32_bf16(a0, b1, acc[0][1], 0, 0, 0);
      acc[1][0] = __builtin_amdgcn_mfma_f32_16x16x32_bf16(a1, b0, acc[1][0], 0, 0, 0);
      acc[1][1] = __builtin_amdgcn_mfma_f32_16x16x32_bf16(a1, b1, acc[1][1], 0, 0, 0);
    }
  }
#pragma unroll
  for (int mi = 0; mi < 2; mi++) {
#pragma unroll
    for (int j = 0; j < 4; j++) {
      int row = m0 + wm * 32 + mi * 16 + kg * 4 + j;
#pragma unroll
      for (int ni = 0; ni < 2; ni++) {
        int col = n0 + wn * 32 + ni * 16 + lr;
        float v = acc[mi][ni][j];
        if (BIAS) v += bias[col];
        if (RES) v += res[(size_t)row * N + col];
        C[(size_t)row * N + col] = v;
      }
    }
  }
}

// ---------------- causal flash attention (bf16 MFMA) ----------------
__global__ __launch_bounds__(256) void attn_mfma(const float* __restrict__ Qb,
                                                 const float* __restrict__ Kb,
                                                 const float* __restrict__ Vb,
                                                 u16* __restrict__ Ob) {
  int qt = (gridDim.x - 1 - blockIdx.x) * 64;  // long blocks first
  int h = blockIdx.y, b = blockIdx.z;
  int t = threadIdx.x;
  int w = t >> 6, lane = t & 63;
  int lr = lane & 15, kg = lane >> 4;
  __shared__ u16 Ks[64][72];
  __shared__ u16 Vs[64][66];   // transposed: [d][key], pitch 66 -> conflict-free
  __shared__ u16 Ps[4][16][72];
  size_t base = (size_t)(b * SEQ) * DMODEL + (size_t)h * DHEAD;
  short8 aq0, aq1;
  {
    const float* qrow = Qb + base + (size_t)(qt + w * 16 + lr) * DMODEL + kg * 8;
    float4 v0 = *reinterpret_cast<const float4*>(qrow);
    float4 v1 = *reinterpret_cast<const float4*>(qrow + 4);
    float4 v2 = *reinterpret_cast<const float4*>(qrow + 32);
    float4 v3 = *reinterpret_cast<const float4*>(qrow + 36);
    const float sc = 0.125f;
    v0.x *= sc; v0.y *= sc; v0.z *= sc; v0.w *= sc;
    v1.x *= sc; v1.y *= sc; v1.z *= sc; v1.w *= sc;
    v2.x *= sc; v2.y *= sc; v2.z *= sc; v2.w *= sc;
    v3.x *= sc; v3.y *= sc; v3.z *= sc; v3.w *= sc;
    aq0 = pack8(v0, v1);
    aq1 = pack8(v2, v3);
  }
  float m[4], l[4];
#pragma unroll
  for (int j = 0; j < 4; j++) { m[j] = -1e30f; l[j] = 0.f; }
  f32x4 acc_o[4] = {};
  for (int kt = 0; kt <= qt; kt += 64) {
    __syncthreads();
    {
      int r = t >> 2, c0 = (t & 3) * 16;
      const float* krow = Kb + base + (size_t)(kt + r) * DMODEL + c0;
      float4 k0 = *reinterpret_cast<const float4*>(krow);
      float4 k1 = *reinterpret_cast<const float4*>(krow + 4);
      float4 k2 = *reinterpret_cast<const float4*>(krow + 8);
      float4 k3 = *reinterpret_cast<const float4*>(krow + 12);
      *reinterpret_cast<short8*>(&Ks[r][c0]) = pack8(k0, k1);
      *reinterpret_cast<short8*>(&Ks[r][c0 + 8]) = pack8(k2, k3);
      int d = lane;
      int r0v = w * 16;
      const float* vcol = Vb + base + (size_t)(kt + r0v) * DMODEL + d;
#pragma unroll
      for (int i = 0; i < 16; i++)
        Vs[d][r0v + i] = bfbits(vcol[(size_t)i * DMODEL]);
    }
    __syncthreads();
    f32x4 s[4] = {};
#pragma unroll
    for (int c = 0; c < 4; c++) {
      short8 bk0 = *reinterpret_cast<const short8*>(&Ks[c * 16 + lr][kg * 8]);
      short8 bk1 = *reinterpret_cast<const short8*>(&Ks[c * 16 + lr][32 + kg * 8]);
      s[c] = __builtin_amdgcn_mfma_f32_16x16x32_bf16(aq0, bk0, s[c], 0, 0, 0);
      s[c] = __builtin_amdgcn_mfma_f32_16x16x32_bf16(aq1, bk1, s[c], 0, 0, 0);
    }
    if (kt == qt) {
#pragma unroll
      for (int c = 0; c < 4; c++)
#pragma unroll
        for (int j = 0; j < 4; j++)
          if (c * 16 + lr > w * 16 + kg * 4 + j) s[c][j] = -1e30f;
    }
    float mt[4];
#pragma unroll
    for (int j = 0; j < 4; j++)
      mt[j] = fmaxf(fmaxf(s[0][j], s[1][j]), fmaxf(s[2][j], s[3][j]));
#pragma unroll
    for (int off = 1; off < 16; off <<= 1)
#pragma unroll
      for (int j = 0; j < 4; j++) mt[j] = fmaxf(mt[j], __shfl_xor(mt[j], off));
    float corr[4];
#pragma unroll
    for (int j = 0; j < 4; j++) {
      float mn = fmaxf(m[j], mt[j]);
      corr[j] = __expf(m[j] - mn);
      m[j] = mn;
      l[j] *= corr[j];
    }
#pragma unroll
    for (int di = 0; di < 4; di++)
#pragma unroll
      for (int j = 0; j < 4; j++) acc_o[di][j] *= corr[j];
    float ps[4] = {0.f, 0.f, 0.f, 0.f};
#pragma unroll
    for (int c = 0; c < 4; c++)
#pragma unroll
      for (int j = 0; j < 4; j++) {
        float p = __expf(s[c][j] - m[j]);
        ps[j] += p;
        s[c][j] = p;
      }
#pragma unroll
    for (int off = 1; off < 16; off <<= 1)
#pragma unroll
      for (int j = 0; j < 4; j++) ps[j] += __shfl_xor(ps[j], off);
#pragma unroll
    for (int j = 0; j < 4; j++) l[j] += ps[j];
#pragma unroll
    for (int c = 0; c < 4; c++)
#pragma unroll
      for (int j = 0; j < 4; j++)
        Ps[w][kg * 4 + j][c * 16 + lr] = bfbits(s[c][j]);
    short8 pa0 = *reinterpret_cast<const short8*>(&Ps[w][lr][kg * 8]);
    short8 pa1 = *reinterpret_cast<const short8*>(&Ps[w][lr][32 + kg * 8]);
#pragma unroll
    for (int di = 0; di < 4; di++) {
      short8 bv0 = *reinterpret_cast<const short8*>(&Vs[di * 16 + lr][kg * 8]);
      short8 bv1 = *reinterpret_cast<const short8*>(&Vs[di * 16 + lr][32 + kg * 8]);
      acc_o[di] = __builtin_amdgcn_mfma_f32_16x16x32_bf16(pa0, bv0, acc_o[di], 0, 0, 0);
      acc_o[di] = __builtin_amdgcn_mfma_f32_16x16x32_bf16(pa1, bv1, acc_o[di], 0, 0, 0);
    }
  }
#pragma unroll
  for (int j = 0; j < 4; j++) {
    float inv = 1.f / l[j];
    size_t rowoff = base + (size_t)(qt + w * 16 + kg * 4 + j) * DMODEL;
#pragma unroll
    for (int di = 0; di < 4; di++)
      Ob[rowoff + di * 16 + lr] = bfbits(acc_o[di][j] * inv);
  }
}

// ---------------- launch ----------------
extern "C" void kernel_launch(void* const* d_in, const int* in_sizes, int n_in,
                              void* d_out, int out_size, void* d_ws, size_t ws_size,
                              hipStream_t stream) {
  const float* x    = (const float*)d_in[0];
  const float* f_qk = (const float*)d_in[1];
  const float* f_v  = (const float*)d_in[2];
  const float* r_qk = (const float*)d_in[3];
  const float* r_v  = (const float*)d_in[4];
  const float* f_kn = (const float*)d_in[5];
  const float* r_kn = (const float*)d_in[6];
  const float* nemb = (const float*)d_in[7];
  const float* W_all = (const float*)d_in[8];
  const float* b_all = (const float*)d_in[9];
  const float* W_fk  = (const float*)d_in[10];
  const float* b_fk  = (const float*)d_in[11];
  const float* W_rk  = (const float*)d_in[12];
  const float* b_rk  = (const float*)d_in[13];
  const float* W_o   = (const float*)d_in[14];
  const float* ln1s  = (const float*)d_in[15];
  const float* ln1b  = (const float*)d_in[16];
  const float* ln2s  = (const float*)d_in[17];
  const float* ln2b  = (const float*)d_in[18];

  float* ws = (float*)d_ws;
  size_t off = 0;
  auto alloc = [&](size_t nf) { float* p = ws + off; off += nf; return p; };
  float* nx    = alloc((size_t)BS * DMODEL);
  float* nx2   = alloc((size_t)BS * DMODEL);
  float* embn  = alloc(6 * NEXP * DSP);
  float* h_all = alloc((size_t)BS * HALL_N);
  float* h_fk2 = alloc((size_t)BS * DSP);
  float* h_rk2 = alloc((size_t)BS * DSP);
  float* w8    = alloc((size_t)8 * BS * NEXP);
  float* featQ = alloc((size_t)BS * RANK);   // ---- zeroed region start
  float* featK = alloc((size_t)BS * RANK);
  float* featV = alloc((size_t)BS * RANK);
  float* featN = alloc((size_t)BS * RANK);
  float* Qb    = alloc((size_t)BS * DMODEL);
  float* Kb    = alloc((size_t)BS * DMODEL);
  float* Vb    = alloc((size_t)BS * DMODEL); // ---- zeroed region end
  float* scratch = alloc((size_t)BS * DMODEL);  // carved: attnOb / woT (u16)
  float* x1    = alloc((size_t)BS * DMODEL);
  int* lists   = (int*)(ws + off); off += (size_t)8 * NEXP * BS;
  int* counts  = (int*)(ws + off); off += 8 * NEXP;
  u16* nxb  = (u16*)(ws + off); off += (size_t)BS * DMODEL / 2;
  u16* fqb  = (u16*)(ws + off); off += (size_t)BS * RANK / 2;
  u16* fkb  = (u16*)(ws + off); off += (size_t)BS * RANK / 2;
  u16* fvb  = (u16*)(ws + off); off += (size_t)BS * RANK / 2;
  u16* wbuf = (u16*)(ws + off); off += (size_t)NEXP * DMODEL * RANK / 2;
  u16* attnOb = (u16*)scratch;
  u16* woT    = attnOb + (size_t)BS * DMODEL;
  // split-K partial regions (stream-ordered reuse of dead buffers):
  float* partA = featQ;   // W_all partials: 4*BS*HALL_N = 3.1M floats < 4.2M (featQ..featN), dead until memset
  float* partK = Qb;      // W_fk/W_rk partials: 8*BS*DSP = 1.05M floats < 2.1M, Qb dead after attn

  const size_t wstr = (size_t)BS * NEXP;
  const size_t lstr = (size_t)NEXP * BS;

  embnorm_kernel<<<6 * NEXP, DSP, 0, stream>>>(nemb, embn);
  wconv_kernel<<<dim3(DMODEL / 64, DMODEL / 64, 1), 256, 0, stream>>>(W_o, woT, DMODEL, DMODEL);
  ln_kernel<<<BS, 256, 0, stream>>>(x, ln1s, ln1b, nx, nxb);
  // h_all = nx @ W_all + b_all  (split-K fp32)
  gemm_splitk<<<dim3(HALL_N / 64, BS / 64, 4), 256, 0, stream>>>(
      nx, W_all, partA, BS, HALL_N, DMODEL, DMODEL / 4);
  reduce_bias_kernel<<<(BS * HALL_N / 4 + 255) / 256, 256, 0, stream>>>(
      partA, b_all, h_all, BS * HALL_N, HALL_N, 4);

  size_t zero_flts = (size_t)4 * BS * RANK + (size_t)3 * BS * DMODEL;
  hipMemsetAsync(featQ, 0, zero_flts * sizeof(float), stream);

  const int poolOf[8] = {0, 0, 1, 2, 2, 3, 4, 5};
  for (int r = 0; r < 6; r++) {
    route_kernel<<<BS, 64, 0, stream>>>(h_all + r * DSP, HALL_N,
                                        embn + poolOf[r] * NEXP * DSP,
                                        w8 + r * wstr);
    bucket_kernel<<<NEXP, 64, 0, stream>>>(w8 + r * wstr, lists + r * lstr,
                                           counts + r * NEXP);
  }

  dim3 gFeat(RANK / 64, NEXP, BS / 128);
  dim3 gRest(DMODEL / 64, NEXP, BS / 128);
  dim3 gWF(RANK / 64, DMODEL / 64, NEXP);
  dim3 gWR(DMODEL / 64, RANK / 64, NEXP);

  // features (K=1024 -> R=512)
  wconv_kernel<<<gWF, 256, 0, stream>>>(f_qk, wbuf, DMODEL, RANK);
  expert_gemm_mfma<<<gFeat, 256, 0, stream>>>(nxb, wbuf, w8 + 0 * wstr,
                                              lists + 0 * lstr, counts + 0 * NEXP,
                                              featQ, DMODEL, RANK);
  expert_gemm_mfma<<<gFeat, 256, 0, stream>>>(nxb, wbuf, w8 + 1 * wstr,
                                              lists + 1 * lstr, counts + 1 * NEXP,
                                              featK, DMODEL, RANK);
  wconv_kernel<<<gWF, 256, 0, stream>>>(f_v, wbuf, DMODEL, RANK);
  expert_gemm_mfma<<<gFeat, 256, 0, stream>>>(nxb, wbuf, w8 + 2 * wstr,
                                              lists + 2 * lstr, counts + 2 * NEXP,
                                              featV, DMODEL, RANK);
  f2b_kernel<<<(BS * RANK / 4 + 255) / 256, 256, 0, stream>>>(featQ, fqb, BS * RANK / 4);
  f2b_kernel<<<(BS * RANK / 4 + 255) / 256, 256, 0, stream>>>(featK, fkb, BS * RANK / 4);
  f2b_kernel<<<(BS * RANK / 4 + 255) / 256, 256, 0, stream>>>(featV, fvb, BS * RANK / 4);
  // restores (K=512 -> D=1024)
  wconv_kernel<<<gWR, 256, 0, stream>>>(r_qk, wbuf, RANK, DMODEL);
  expert_gemm_mfma<<<gRest, 256, 0, stream>>>(fqb, wbuf, w8 + 3 * wstr,
                                              lists + 3 * lstr, counts + 3 * NEXP,
                                              Qb, RANK, DMODEL);
  expert_gemm_mfma<<<gRest, 256, 0, stream>>>(fkb, wbuf, w8 + 4 * wstr,
                                              lists + 4 * lstr, counts + 4 * NEXP,
                                              Kb, RANK, DMODEL);
  wconv_kernel<<<gWR, 256, 0, stream>>>(r_v, wbuf, RANK, DMODEL);
  expert_gemm_mfma<<<gRest, 256, 0, stream>>>(fvb, wbuf, w8 + 5 * wstr,
                                              lists + 5 * lstr, counts + 5 * NEXP,
                                              Vb, RANK, DMODEL);

  attn_mfma<<<dim3(SEQ / 64, NHEAD, BATCH), 256, 0, stream>>>(Qb, Kb, Vb, attnOb);

  // x1 = x + attnO @ W_o   (bf16 MFMA)
  dense_gemm_mfma<false, true><<<dim3(DMODEL / 64, BS / 64), 256, 0, stream>>>(
      attnOb, woT, nullptr, x, x1, BS, DMODEL, DMODEL);

  // knowledge circuit
  ln_kernel<<<BS, 256, 0, stream>>>(x1, ln2s, ln2b, nx2, nxb);
  gemm_splitk<<<dim3(1, BS / 64, 8), 256, 0, stream>>>(
      nx2, W_fk, partK, BS, DSP, DMODEL, DMODEL / 8);
  reduce_bias_kernel<<<(BS * DSP / 4 + 255) / 256, 256, 0, stream>>>(
      partK, b_fk, h_fk2, BS * DSP, DSP, 8);
  route_kernel<<<BS, 64, 0, stream>>>(h_fk2, DSP, embn + 4 * NEXP * DSP, w8 + 6 * wstr);
  bucket_kernel<<<NEXP, 64, 0, stream>>>(w8 + 6 * wstr, lists + 6 * lstr, counts + 6 * NEXP);
  gemm_splitk<<<dim3(1, BS / 64, 8), 256, 0, stream>>>(
      nx2, W_rk, partK, BS, DSP, DMODEL, DMODEL / 8);
  reduce_bias_kernel<<<(BS * DSP / 4 + 255) / 256, 256, 0, stream>>>(
      partK, b_rk, h_rk2, BS * DSP, DSP, 8);
  route_kernel<<<BS, 64, 0, stream>>>(h_rk2, DSP, embn + 5 * NEXP * DSP, w8 + 7 * wstr);
  bucket_kernel<<<NEXP, 64, 0, stream>>>(w8 + 7 * wstr, lists + 7 * lstr, counts + 7 * NEXP);

  wconv_kernel<<<gWF, 256, 0, stream>>>(f_kn, wbuf, DMODEL, RANK);
  expert_gemm_mfma<<<gFeat, 256, 0, stream>>>(nxb, wbuf, w8 + 6 * wstr,
                                              lists + 6 * lstr, counts + 6 * NEXP,
                                              featN, DMODEL, RANK);
  f2b_kernel<<<(BS * RANK / 4 + 255) / 256, 256, 0, stream>>>(featN, fqb, BS * RANK / 4);
  wconv_kernel<<<gWR, 256, 0, stream>>>(r_kn, wbuf, RANK, DMODEL);
  hipMemcpyAsync(d_out, x1, (size_t)BS * DMODEL * sizeof(float),
                 hipMemcpyDeviceToDevice, stream);
  expert_gemm_mfma<<<gRest, 256, 0, stream>>>(fqb, wbuf, w8 + 7 * wstr,
                                              lists + 7 * lstr, counts + 7 * NEXP,
                                              (float*)d_out, RANK, DMODEL);
}

// Round 6
// 666.109 us; speedup vs baseline: 7.5036x; 1.1064x over previous
//
#include <hip/hip_runtime.h>
#include <hip/hip_bf16.h>
#include <cstdint>

#define BS     2048   // B*S tokens
#define DMODEL 1024
#define RANK   512
#define NEXP   32
#define DSP    64
#define NHEAD  16
#define DHEAD  64
#define SEQ    1024
#define BATCH  2
#define HALL_N 384    // 6*DSP

typedef unsigned short u16;
typedef __attribute__((ext_vector_type(8))) short short8;
typedef __attribute__((ext_vector_type(4))) float f32x4;

__device__ __forceinline__ u16 bfbits(float x) {
  __hip_bfloat16 h = __float2bfloat16(x);
  return __builtin_bit_cast(u16, h);
}

// ---------------- LayerNorm (token per block, 256 thr, float4), fp32 + bf16 out ----
__global__ void ln_kernel(const float* __restrict__ x,
                          const float* __restrict__ sc,
                          const float* __restrict__ bi,
                          float* __restrict__ out,
                          u16* __restrict__ outb) {
  int tok = blockIdx.x;
  int t = threadIdx.x; // 256
  const float4* xr = reinterpret_cast<const float4*>(x + (size_t)tok * DMODEL);
  float4 v = xr[t];
  float s = v.x + v.y + v.z + v.w;
  float q = v.x * v.x + v.y * v.y + v.z * v.z + v.w * v.w;
#pragma unroll
  for (int off = 32; off > 0; off >>= 1) {
    s += __shfl_xor(s, off);
    q += __shfl_xor(q, off);
  }
  __shared__ float red[8];
  int wid = t >> 6;
  if ((t & 63) == 0) { red[wid] = s; red[4 + wid] = q; }
  __syncthreads();
  s = red[0] + red[1] + red[2] + red[3];
  q = red[4] + red[5] + red[6] + red[7];
  float mu = s * (1.f / DMODEL);
  float var = q * (1.f / DMODEL) - mu * mu;
  float inv = rsqrtf(var + 1e-6f);
  float4 scv = reinterpret_cast<const float4*>(sc)[t];
  float4 biv = reinterpret_cast<const float4*>(bi)[t];
  float4 r;
  r.x = (v.x - mu) * inv * scv.x + biv.x;
  r.y = (v.y - mu) * inv * scv.y + biv.y;
  r.z = (v.z - mu) * inv * scv.z + biv.z;
  r.w = (v.w - mu) * inv * scv.w + biv.w;
  reinterpret_cast<float4*>(out + (size_t)tok * DMODEL)[t] = r;
  ushort4 ob;
  ob.x = bfbits(r.x); ob.y = bfbits(r.y); ob.z = bfbits(r.z); ob.w = bfbits(r.w);
  reinterpret_cast<ushort4*>(outb + (size_t)tok * DMODEL)[t] = ob;
}

// ---------------- emb row L2-normalize ----------------
__global__ void embnorm_kernel(const float* __restrict__ e, float* __restrict__ o) {
  int row = blockIdx.x;
  int lane = threadIdx.x; // 64
  float v = e[row * DSP + lane];
  float q = v * v;
#pragma unroll
  for (int off = 32; off > 0; off >>= 1) q += __shfl_xor(q, off);
  o[row * DSP + lane] = v / (sqrtf(q) + 1e-8f);
}

// ---------------- fp32 split-K GEMM: part[ks] = A[M,Kc]@B[Kc,N] ----------------
__global__ __launch_bounds__(256) void gemm_splitk(const float* __restrict__ A,
                                                   const float* __restrict__ Bm,
                                                   float* __restrict__ part,
                                                   int M, int N, int K, int kchunk) {
  __shared__ float As[16][65];
  __shared__ float Bs[16][64];
  int n0 = blockIdx.x * 64;
  int m0 = blockIdx.y * 64;
  int kbeg = blockIdx.z * kchunk;
  int t = threadIdx.x;
  int tx = t & 15, ty = t >> 4;
  float c[4][4] = {};
  for (int k0 = kbeg; k0 < kbeg + kchunk; k0 += 16) {
#pragma unroll
    for (int i = 0; i < 4; i++) {
      int idx = t + i * 256;
      int m = idx >> 4, kk = idx & 15;
      As[kk][m] = A[(size_t)(m0 + m) * K + k0 + kk];
    }
#pragma unroll
    for (int i = 0; i < 4; i++) {
      int idx = t + i * 256;
      int kk = idx >> 6, nn = idx & 63;
      Bs[kk][nn] = Bm[(size_t)(k0 + kk) * N + n0 + nn];
    }
    __syncthreads();
#pragma unroll
    for (int kk = 0; kk < 16; kk++) {
      float a[4], b[4];
#pragma unroll
      for (int i = 0; i < 4; i++) a[i] = As[kk][ty + i * 16];
#pragma unroll
      for (int j = 0; j < 4; j++) b[j] = Bs[kk][tx + j * 16];
#pragma unroll
      for (int i = 0; i < 4; i++)
#pragma unroll
        for (int j = 0; j < 4; j++) c[i][j] += a[i] * b[j];
    }
    __syncthreads();
  }
  float* po = part + (size_t)blockIdx.z * M * N;
#pragma unroll
  for (int i = 0; i < 4; i++)
#pragma unroll
    for (int j = 0; j < 4; j++)
      po[(size_t)(m0 + ty + i * 16) * N + n0 + tx + j * 16] = c[i][j];
}

// ---------------- split-K reduce + bias ----------------
__global__ void reduce_bias_kernel(const float* __restrict__ part,
                                   const float* __restrict__ bias,
                                   float* __restrict__ out,
                                   int MN, int N, int KS) {
  int i = blockIdx.x * 256 + threadIdx.x;
  if (i * 4 >= MN) return;
  float4 s = reinterpret_cast<const float4*>(part)[i];
  for (int ks = 1; ks < KS; ks++) {
    float4 p = reinterpret_cast<const float4*>(part + (size_t)ks * MN)[i];
    s.x += p.x; s.y += p.y; s.z += p.z; s.w += p.w;
  }
  int col = (i * 4) % N;
  float4 b = *reinterpret_cast<const float4*>(bias + col);
  s.x += b.x; s.y += b.y; s.z += b.z; s.w += b.w;
  reinterpret_cast<float4*>(out)[i] = s;
}

// ---------------- routing: softmax over 32 logits, top-4, renormalize ----------------
__global__ void route_kernel(const float* __restrict__ h, int ldh,
                             const float* __restrict__ e, // [32,64] normalized, pre-offset
                             float* __restrict__ wout) {  // [BS,32]
  int tok = blockIdx.x;
  int lane = threadIdx.x; // 64
  __shared__ float hs[DSP];
  __shared__ float es[NEXP * DSP];
  hs[lane] = h[(size_t)tok * ldh + lane];
#pragma unroll
  for (int i = 0; i < NEXP * DSP / 64; i++) es[lane + i * 64] = e[lane + i * 64];
  __syncthreads();
  float logit = -1e30f;
  if (lane < NEXP) {
    float s = 0.f;
#pragma unroll
    for (int d = 0; d < DSP; d++) s += hs[d] * es[lane * DSP + d];
    logit = s;
  }
  float mx = logit;
#pragma unroll
  for (int off = 16; off > 0; off >>= 1) mx = fmaxf(mx, __shfl_xor(mx, off));
  float p = (lane < NEXP) ? __expf(logit - mx) : 0.f;
  float sum = p;
#pragma unroll
  for (int off = 16; off > 0; off >>= 1) sum += __shfl_xor(sum, off);
  p = p / sum;
  float val = p;
  float chosen = 0.f;
  float selsum = 0.f;
#pragma unroll
  for (int it = 0; it < 4; it++) {
    float v = val;
    int vi = lane;
#pragma unroll
    for (int off = 16; off > 0; off >>= 1) {
      float ov = __shfl_xor(v, off);
      int oi = __shfl_xor(vi, off);
      if (ov > v || (ov == v && oi < vi)) { v = ov; vi = oi; }
    }
    if (lane == vi) { chosen = p; val = -1.f; }
    selsum += v;
  }
  if (lane < NEXP) wout[(size_t)tok * NEXP + lane] = chosen / (selsum + 1e-8f);
}

// ------- per-expert token list + slot map (ballot compaction, deterministic) -------
__global__ void bucket_kernel(const float* __restrict__ w, // [BS,32]
                              int* __restrict__ list,      // [32,BS]
                              int* __restrict__ slotmap,   // [32,BS] local slot of tok
                              int* __restrict__ count) {   // [32]
  int n = blockIdx.x;
  int lane = threadIdx.x; // 64
  int base = 0;
  for (int t0 = 0; t0 < BS; t0 += 64) {
    int tok = t0 + lane;
    bool act = (w[(size_t)tok * NEXP + n] != 0.f);
    unsigned long long mask = __ballot(act);
    int pos = __popcll(mask & ((1ull << lane) - 1ull));
    if (act) {
      list[n * BS + base + pos] = tok;
      slotmap[n * BS + tok] = base + pos;
    }
    base += __popcll(mask);
  }
  if (lane == 0) count[n] = base;
}

// ---------------- exclusive scan of 32 counts per route ----------------
__global__ void scan32_kernel(const int* __restrict__ counts, int* __restrict__ offs) {
  int r = blockIdx.x;
  int lane = threadIdx.x; // 64
  int c = (lane < NEXP) ? counts[r * NEXP + lane] : 0;
  int s = c;
#pragma unroll
  for (int d = 1; d < NEXP; d <<= 1) {
    int o = __shfl_up(s, d);
    if (lane >= d) s += o;
  }
  if (lane < NEXP) offs[r * NEXP + lane] = s - c;
}

// ---------------- weight convert+transpose: F[e][K][NOUT] f32 -> FT[e][NOUT][K] bf16 ----
__global__ void wconv_kernel(const float* __restrict__ F, u16* __restrict__ FT,
                             int K, int NOUT) {
  int e = blockIdx.z;
  int n0 = blockIdx.x * 64, k0 = blockIdx.y * 64;
  const float* Fe = F + (size_t)e * K * NOUT;
  u16* FTe = FT + (size_t)e * K * NOUT;
  __shared__ u16 tile[64][72];
  int t = threadIdx.x; // 256
  int kr = t >> 4, nc = (t & 15) * 4;
#pragma unroll
  for (int p = 0; p < 4; p++) {
    int kk = kr + p * 16;
    float4 v = *reinterpret_cast<const float4*>(Fe + (size_t)(k0 + kk) * NOUT + n0 + nc);
    tile[nc + 0][kk] = bfbits(v.x);
    tile[nc + 1][kk] = bfbits(v.y);
    tile[nc + 2][kk] = bfbits(v.z);
    tile[nc + 3][kk] = bfbits(v.w);
  }
  __syncthreads();
  int nr = t >> 2, c0 = (t & 3) * 16;
  u16* dst = FTe + (size_t)(n0 + nr) * K + k0 + c0;
  *reinterpret_cast<short8*>(dst) = *reinterpret_cast<const short8*>(&tile[nr][c0]);
  *reinterpret_cast<short8*>(dst + 8) = *reinterpret_cast<const short8*>(&tile[nr][c0 + 8]);
}

// ---------------- expert-major grouped GEMM (bf16 MFMA, 128x64 tile) ----------------
// Writes UNWEIGHTED compact rows: Cout[offs[n] + local][NOUT]; no atomics, no zero-init.
__global__ __launch_bounds__(256) void expert_gemm_mfma(
    const u16* __restrict__ Xb,    // [BS][K] bf16
    const u16* __restrict__ FT,    // [32][NOUT][K] bf16
    const int* __restrict__ list,  // [32,BS]
    const int* __restrict__ count, // [32]
    const int* __restrict__ offs,  // [32] exclusive scan
    float* __restrict__ Cout,      // [4*BS][NOUT] fp32 compact
    int K, int NOUT) {
  int n = blockIdx.y;
  int cnt = count[n];
  int m0 = blockIdx.z * 128;
  if (m0 >= cnt) return;
  int n0 = blockIdx.x * 64;
  __shared__ u16 Xs[128][72];
  __shared__ u16 Fs[64][72];
  __shared__ int toks[128];
  int t = threadIdx.x;
  if (t < 128) toks[t] = (m0 + t < cnt) ? list[n * BS + m0 + t] : -1;
  __syncthreads();
  const u16* FTe = FT + ((size_t)n * NOUT + n0) * K;
  int wave = t >> 6, lane = t & 63;
  int wm = wave >> 1, wn = wave & 1;
  int lr = lane & 15, kg = lane >> 4;
  f32x4 acc[4][2] = {};
  int xri = t >> 1, xc = (t & 1) * 32;
  int tokr = toks[xri];
  const u16* xrow = Xb + (size_t)(tokr < 0 ? 0 : tokr) * K + xc;
  int fri = t >> 2, fc = (t & 3) * 16;
  const u16* frow = FTe + (size_t)fri * K + fc;
  for (int k0 = 0; k0 < K; k0 += 64) {
    short8 xv0 = {}, xv1 = {}, xv2 = {}, xv3 = {};
    if (tokr >= 0) {
      xv0 = *reinterpret_cast<const short8*>(xrow + k0);
      xv1 = *reinterpret_cast<const short8*>(xrow + k0 + 8);
      xv2 = *reinterpret_cast<const short8*>(xrow + k0 + 16);
      xv3 = *reinterpret_cast<const short8*>(xrow + k0 + 24);
    }
    short8 fv0 = *reinterpret_cast<const short8*>(frow + k0);
    short8 fv1 = *reinterpret_cast<const short8*>(frow + k0 + 8);
    __syncthreads();
    *reinterpret_cast<short8*>(&Xs[xri][xc]) = xv0;
    *reinterpret_cast<short8*>(&Xs[xri][xc + 8]) = xv1;
    *reinterpret_cast<short8*>(&Xs[xri][xc + 16]) = xv2;
    *reinterpret_cast<short8*>(&Xs[xri][xc + 24]) = xv3;
    *reinterpret_cast<short8*>(&Fs[fri][fc]) = fv0;
    *reinterpret_cast<short8*>(&Fs[fri][fc + 8]) = fv1;
    __syncthreads();
#pragma unroll
    for (int kk = 0; kk < 2; kk++) {
      short8 b0 = *reinterpret_cast<const short8*>(&Fs[wn * 32 + lr][kk * 32 + kg * 8]);
      short8 b1 = *reinterpret_cast<const short8*>(&Fs[wn * 32 + 16 + lr][kk * 32 + kg * 8]);
#pragma unroll
      for (int mi = 0; mi < 4; mi++) {
        short8 a = *reinterpret_cast<const short8*>(&Xs[wm * 64 + mi * 16 + lr][kk * 32 + kg * 8]);
        acc[mi][0] = __builtin_amdgcn_mfma_f32_16x16x32_bf16(a, b0, acc[mi][0], 0, 0, 0);
        acc[mi][1] = __builtin_amdgcn_mfma_f32_16x16x32_bf16(a, b1, acc[mi][1], 0, 0, 0);
      }
    }
  }
  int gbase = offs[n] + m0;
#pragma unroll
  for (int mi = 0; mi < 4; mi++) {
#pragma unroll
    for (int j = 0; j < 4; j++) {
      int row = wm * 64 + mi * 16 + kg * 4 + j;
      if (toks[row] < 0) continue;
      float* crow = Cout + (size_t)(gbase + row) * NOUT + n0 + wn * 32;
#pragma unroll
      for (int ni = 0; ni < 2; ni++)
        crow[ni * 16 + lr] = acc[mi][ni][j];
    }
  }
}

// ---------------- per-token weighted combine of 4 compact rows ----------------
template <int NOUT, bool FINAL>
__global__ __launch_bounds__(256) void gather_combine(
    const float* __restrict__ C,      // [4*BS][NOUT]
    const float* __restrict__ wr,     // [BS][32] route weights
    const int* __restrict__ slotmap,  // [32][BS]
    const int* __restrict__ offs,     // [32]
    const float* __restrict__ resid,  // [BS][NOUT] (FINAL)
    float* __restrict__ outf,         // fp32 out (FINAL)
    u16* __restrict__ outb) {         // bf16 out (!FINAL)
  int tok = blockIdx.x;
  int t = threadIdx.x;
  __shared__ float lw[4];
  __shared__ int ls[4];
  __shared__ int lcnt;
  if (t < 64) {
    float wv = (t < NEXP) ? wr[(size_t)tok * NEXP + t] : 0.f;
    bool act = wv != 0.f;
    unsigned long long mask = __ballot(act);
    int pos = __popcll(mask & ((1ull << t) - 1ull));
    if (act) { ls[pos] = offs[t] + slotmap[t * BS + tok]; lw[pos] = wv; }
    if (t == 0) lcnt = __popcll(mask);
  }
  __syncthreads();
  if (t < NOUT / 4) {
    float4 s = {0.f, 0.f, 0.f, 0.f};
    int cnt = lcnt;
    for (int k = 0; k < cnt; k++) {
      float4 v = reinterpret_cast<const float4*>(C + (size_t)ls[k] * NOUT)[t];
      float wk = lw[k];
      s.x += wk * v.x; s.y += wk * v.y; s.z += wk * v.z; s.w += wk * v.w;
    }
    if (FINAL) {
      float4 r = reinterpret_cast<const float4*>(resid + (size_t)tok * NOUT)[t];
      s.x += r.x; s.y += r.y; s.z += r.z; s.w += r.w;
      reinterpret_cast<float4*>(outf + (size_t)tok * NOUT)[t] = s;
    } else {
      ushort4 o;
      o.x = bfbits(s.x); o.y = bfbits(s.y); o.z = bfbits(s.z); o.w = bfbits(s.w);
      reinterpret_cast<ushort4*>(outb + (size_t)tok * NOUT)[t] = o;
    }
  }
}

// ---------------- dense bf16 MFMA GEMM: C = A@B (+bias)(+res), BT = B^T [N][K] ------
template <bool BIAS, bool RES>
__global__ __launch_bounds__(256) void dense_gemm_mfma(
    const u16* __restrict__ Ab,   // [M][K] bf16
    const u16* __restrict__ BT,   // [N][K] bf16
    const float* __restrict__ bias,
    const float* __restrict__ res,
    float* __restrict__ C, int M, int N, int K) {
  int n0 = blockIdx.x * 64, m0 = blockIdx.y * 64;
  __shared__ u16 Xs[64][72];
  __shared__ u16 Fs[64][72];
  int t = threadIdx.x;
  int wave = t >> 6, lane = t & 63;
  int wm = wave >> 1, wn = wave & 1;
  int lr = lane & 15, kg = lane >> 4;
  f32x4 acc[2][2] = {};
  int srow = t >> 2, sc = (t & 3) * 16;
  const u16* xrow = Ab + (size_t)(m0 + srow) * K + sc;
  const u16* frow = BT + (size_t)(n0 + srow) * K + sc;
  for (int k0 = 0; k0 < K; k0 += 64) {
    short8 xv0 = *reinterpret_cast<const short8*>(xrow + k0);
    short8 xv1 = *reinterpret_cast<const short8*>(xrow + k0 + 8);
    short8 fv0 = *reinterpret_cast<const short8*>(frow + k0);
    short8 fv1 = *reinterpret_cast<const short8*>(frow + k0 + 8);
    __syncthreads();
    *reinterpret_cast<short8*>(&Xs[srow][sc]) = xv0;
    *reinterpret_cast<short8*>(&Xs[srow][sc + 8]) = xv1;
    *reinterpret_cast<short8*>(&Fs[srow][sc]) = fv0;
    *reinterpret_cast<short8*>(&Fs[srow][sc + 8]) = fv1;
    __syncthreads();
#pragma unroll
    for (int kk = 0; kk < 2; kk++) {
      short8 a0 = *reinterpret_cast<const short8*>(&Xs[wm * 32 + lr][kk * 32 + kg * 8]);
      short8 a1 = *reinterpret_cast<const short8*>(&Xs[wm * 32 + 16 + lr][kk * 32 + kg * 8]);
      short8 b0 = *reinterpret_cast<const short8*>(&Fs[wn * 32 + lr][kk * 32 + kg * 8]);
      short8 b1 = *reinterpret_cast<const short8*>(&Fs[wn * 32 + 16 + lr][kk * 32 + kg * 8]);
      acc[0][0] = __builtin_amdgcn_mfma_f32_16x16x32_bf16(a0, b0, acc[0][0], 0, 0, 0);
      acc[0][1] = __builtin_amdgcn_mfma_f32_16x16x32_bf16(a0, b1, acc[0][1], 0, 0, 0);
      acc[1][0] = __builtin_amdgcn_mfma_f32_16x16x32_bf16(a1, b0, acc[1][0], 0, 0, 0);
      acc[1][1] = __builtin_amdgcn_mfma_f32_16x16x32_bf16(a1, b1, acc[1][1], 0, 0, 0);
    }
  }
#pragma unroll
  for (int mi = 0; mi < 2; mi++) {
#pragma unroll
    for (int j = 0; j < 4; j++) {
      int row = m0 + wm * 32 + mi * 16 + kg * 4 + j;
#pragma unroll
      for (int ni = 0; ni < 2; ni++) {
        int col = n0 + wn * 32 + ni * 16 + lr;
        float v = acc[mi][ni][j];
        if (BIAS) v += bias[col];
        if (RES) v += res[(size_t)row * N + col];
        C[(size_t)row * N + col] = v;
      }
    }
  }
}

// ---------------- causal flash attention (bf16 MFMA, bf16 inputs) ----------------
__global__ __launch_bounds__(256) void attn_mfma(const u16* __restrict__ Qb,
                                                 const u16* __restrict__ Kb,
                                                 const u16* __restrict__ Vb,
                                                 u16* __restrict__ Ob) {
  int qt = (gridDim.x - 1 - blockIdx.x) * 64;  // long blocks first
  int h = blockIdx.y, b = blockIdx.z;
  int t = threadIdx.x;
  int w = t >> 6, lane = t & 63;
  int lr = lane & 15, kg = lane >> 4;
  __shared__ u16 Ks[64][72];
  __shared__ u16 Vs[64][66];   // transposed: [d][key], pitch 66 -> conflict-free
  __shared__ u16 Ps[4][16][72];
  size_t base = (size_t)(b * SEQ) * DMODEL + (size_t)h * DHEAD;
  const u16* qrow = Qb + base + (size_t)(qt + w * 16 + lr) * DMODEL + kg * 8;
  short8 aq0 = *reinterpret_cast<const short8*>(qrow);
  short8 aq1 = *reinterpret_cast<const short8*>(qrow + 32);
  float m[4], l[4];
#pragma unroll
  for (int j = 0; j < 4; j++) { m[j] = -1e30f; l[j] = 0.f; }
  f32x4 acc_o[4] = {};
  for (int kt = 0; kt <= qt; kt += 64) {
    __syncthreads();
    {
      int r = t >> 2, c0 = (t & 3) * 16;
      const u16* krow = Kb + base + (size_t)(kt + r) * DMODEL + c0;
      *reinterpret_cast<short8*>(&Ks[r][c0]) = *reinterpret_cast<const short8*>(krow);
      *reinterpret_cast<short8*>(&Ks[r][c0 + 8]) = *reinterpret_cast<const short8*>(krow + 8);
      int d = lane;
      int r0v = w * 16;
      const u16* vcol = Vb + base + (size_t)(kt + r0v) * DMODEL + d;
#pragma unroll
      for (int i = 0; i < 16; i++)
        Vs[d][r0v + i] = vcol[(size_t)i * DMODEL];
    }
    __syncthreads();
    f32x4 s[4] = {};
#pragma unroll
    for (int c = 0; c < 4; c++) {
      short8 bk0 = *reinterpret_cast<const short8*>(&Ks[c * 16 + lr][kg * 8]);
      short8 bk1 = *reinterpret_cast<const short8*>(&Ks[c * 16 + lr][32 + kg * 8]);
      s[c] = __builtin_amdgcn_mfma_f32_16x16x32_bf16(aq0, bk0, s[c], 0, 0, 0);
      s[c] = __builtin_amdgcn_mfma_f32_16x16x32_bf16(aq1, bk1, s[c], 0, 0, 0);
    }
#pragma unroll
    for (int c = 0; c < 4; c++)
#pragma unroll
      for (int j = 0; j < 4; j++) s[c][j] *= 0.125f;  // 1/sqrt(64)
    if (kt == qt) {
#pragma unroll
      for (int c = 0; c < 4; c++)
#pragma unroll
        for (int j = 0; j < 4; j++)
          if (c * 16 + lr > w * 16 + kg * 4 + j) s[c][j] = -1e30f;
    }
    float mt[4];
#pragma unroll
    for (int j = 0; j < 4; j++)
      mt[j] = fmaxf(fmaxf(s[0][j], s[1][j]), fmaxf(s[2][j], s[3][j]));
#pragma unroll
    for (int off = 1; off < 16; off <<= 1)
#pragma unroll
      for (int j = 0; j < 4; j++) mt[j] = fmaxf(mt[j], __shfl_xor(mt[j], off));
    float corr[4];
#pragma unroll
    for (int j = 0; j < 4; j++) {
      float mn = fmaxf(m[j], mt[j]);
      corr[j] = __expf(m[j] - mn);
      m[j] = mn;
      l[j] *= corr[j];
    }
#pragma unroll
    for (int di = 0; di < 4; di++)
#pragma unroll
      for (int j = 0; j < 4; j++) acc_o[di][j] *= corr[j];
    float ps[4] = {0.f, 0.f, 0.f, 0.f};
#pragma unroll
    for (int c = 0; c < 4; c++)
#pragma unroll
      for (int j = 0; j < 4; j++) {
        float p = __expf(s[c][j] - m[j]);
        ps[j] += p;
        s[c][j] = p;
      }
#pragma unroll
    for (int off = 1; off < 16; off <<= 1)
#pragma unroll
      for (int j = 0; j < 4; j++) ps[j] += __shfl_xor(ps[j], off);
#pragma unroll
    for (int j = 0; j < 4; j++) l[j] += ps[j];
#pragma unroll
    for (int c = 0; c < 4; c++)
#pragma unroll
      for (int j = 0; j < 4; j++)
        Ps[w][kg * 4 + j][c * 16 + lr] = bfbits(s[c][j]);
    short8 pa0 = *reinterpret_cast<const short8*>(&Ps[w][lr][kg * 8]);
    short8 pa1 = *reinterpret_cast<const short8*>(&Ps[w][lr][32 + kg * 8]);
#pragma unroll
    for (int di = 0; di < 4; di++) {
      short8 bv0 = *reinterpret_cast<const short8*>(&Vs[di * 16 + lr][kg * 8]);
      short8 bv1 = *reinterpret_cast<const short8*>(&Vs[di * 16 + lr][32 + kg * 8]);
      acc_o[di] = __builtin_amdgcn_mfma_f32_16x16x32_bf16(pa0, bv0, acc_o[di], 0, 0, 0);
      acc_o[di] = __builtin_amdgcn_mfma_f32_16x16x32_bf16(pa1, bv1, acc_o[di], 0, 0, 0);
    }
  }
#pragma unroll
  for (int j = 0; j < 4; j++) {
    float inv = 1.f / l[j];
    size_t rowoff = base + (size_t)(qt + w * 16 + kg * 4 + j) * DMODEL;
#pragma unroll
    for (int di = 0; di < 4; di++)
      Ob[rowoff + di * 16 + lr] = bfbits(acc_o[di][j] * inv);
  }
}

// ---------------- launch ----------------
extern "C" void kernel_launch(void* const* d_in, const int* in_sizes, int n_in,
                              void* d_out, int out_size, void* d_ws, size_t ws_size,
                              hipStream_t stream) {
  const float* x    = (const float*)d_in[0];
  const float* f_qk = (const float*)d_in[1];
  const float* f_v  = (const float*)d_in[2];
  const float* r_qk = (const float*)d_in[3];
  const float* r_v  = (const float*)d_in[4];
  const float* f_kn = (const float*)d_in[5];
  const float* r_kn = (const float*)d_in[6];
  const float* nemb = (const float*)d_in[7];
  const float* W_all = (const float*)d_in[8];
  const float* b_all = (const float*)d_in[9];
  const float* W_fk  = (const float*)d_in[10];
  const float* b_fk  = (const float*)d_in[11];
  const float* W_rk  = (const float*)d_in[12];
  const float* b_rk  = (const float*)d_in[13];
  const float* W_o   = (const float*)d_in[14];
  const float* ln1s  = (const float*)d_in[15];
  const float* ln1b  = (const float*)d_in[16];
  const float* ln2s  = (const float*)d_in[17];
  const float* ln2b  = (const float*)d_in[18];

  float* ws = (float*)d_ws;
  size_t off = 0;
  auto alloc = [&](size_t nf) { float* p = ws + off; off += nf; return p; };
  float* nx      = alloc((size_t)BS * DMODEL);
  float* nx2     = alloc((size_t)BS * DMODEL);
  float* embn    = alloc(6 * NEXP * DSP);
  float* h_all   = alloc((size_t)BS * HALL_N);
  float* h_fk2   = alloc((size_t)BS * DSP);
  float* h_rk2   = alloc((size_t)BS * DSP);
  float* w8      = alloc((size_t)8 * BS * NEXP);
  float* x1      = alloc((size_t)BS * DMODEL);
  float* compactF = alloc((size_t)4 * BS * RANK);    // 8192 x 512
  float* compactR = alloc((size_t)4 * BS * DMODEL);  // 8192 x 1024 (also split-K partials)
  int* lists   = (int*)(ws + off); off += (size_t)8 * NEXP * BS;
  int* slotmap = (int*)(ws + off); off += (size_t)8 * NEXP * BS;
  int* counts  = (int*)(ws + off); off += 8 * NEXP;
  int* offsb   = (int*)(ws + off); off += 8 * NEXP;
  u16* nxb  = (u16*)(ws + off); off += (size_t)BS * DMODEL / 2;
  u16* fqb  = (u16*)(ws + off); off += (size_t)BS * RANK / 2;
  u16* fkb  = (u16*)(ws + off); off += (size_t)BS * RANK / 2;
  u16* fvb  = (u16*)(ws + off); off += (size_t)BS * RANK / 2;
  u16* fnb  = (u16*)(ws + off); off += (size_t)BS * RANK / 2;
  u16* Qbb  = (u16*)(ws + off); off += (size_t)BS * DMODEL / 2;
  u16* Kbb  = (u16*)(ws + off); off += (size_t)BS * DMODEL / 2;
  u16* Vbb  = (u16*)(ws + off); off += (size_t)BS * DMODEL / 2;
  u16* attnOb = (u16*)(ws + off); off += (size_t)BS * DMODEL / 2;
  u16* woT  = (u16*)(ws + off); off += (size_t)DMODEL * DMODEL / 2;
  u16* wbuf = (u16*)(ws + off); off += (size_t)NEXP * DMODEL * RANK / 2;
  float* partA = compactR;  // W_all partials: 4*BS*384 = 3.1M fl < 8.4M
  float* partK = compactR;  // W_fk/W_rk partials: 8*BS*64 = 1.05M fl

  const size_t wstr = (size_t)BS * NEXP;
  const size_t lstr = (size_t)NEXP * BS;

  embnorm_kernel<<<6 * NEXP, DSP, 0, stream>>>(nemb, embn);
  wconv_kernel<<<dim3(DMODEL / 64, DMODEL / 64, 1), 256, 0, stream>>>(W_o, woT, DMODEL, DMODEL);
  ln_kernel<<<BS, 256, 0, stream>>>(x, ln1s, ln1b, nx, nxb);
  gemm_splitk<<<dim3(HALL_N / 64, BS / 64, 4), 256, 0, stream>>>(
      nx, W_all, partA, BS, HALL_N, DMODEL, DMODEL / 4);
  reduce_bias_kernel<<<(BS * HALL_N / 4 + 255) / 256, 256, 0, stream>>>(
      partA, b_all, h_all, BS * HALL_N, HALL_N, 4);

  const int poolOf[8] = {0, 0, 1, 2, 2, 3, 4, 5};
  for (int r = 0; r < 6; r++) {
    route_kernel<<<BS, 64, 0, stream>>>(h_all + r * DSP, HALL_N,
                                        embn + poolOf[r] * NEXP * DSP,
                                        w8 + r * wstr);
    bucket_kernel<<<NEXP, 64, 0, stream>>>(w8 + r * wstr, lists + r * lstr,
                                           slotmap + r * lstr, counts + r * NEXP);
  }
  scan32_kernel<<<6, 64, 0, stream>>>(counts, offsb);

  dim3 gFeat(RANK / 64, NEXP, BS / 128);
  dim3 gRest(DMODEL / 64, NEXP, BS / 128);
  dim3 gWF(RANK / 64, DMODEL / 64, NEXP);
  dim3 gWR(DMODEL / 64, RANK / 64, NEXP);

  // features (K=1024 -> R=512), compact + gather to bf16
  wconv_kernel<<<gWF, 256, 0, stream>>>(f_qk, wbuf, DMODEL, RANK);
  expert_gemm_mfma<<<gFeat, 256, 0, stream>>>(nxb, wbuf, lists + 0 * lstr,
                                              counts + 0 * NEXP, offsb + 0 * NEXP,
                                              compactF, DMODEL, RANK);
  gather_combine<RANK, false><<<BS, 256, 0, stream>>>(compactF, w8 + 0 * wstr,
      slotmap + 0 * lstr, offsb + 0 * NEXP, nullptr, nullptr, fqb);
  expert_gemm_mfma<<<gFeat, 256, 0, stream>>>(nxb, wbuf, lists + 1 * lstr,
                                              counts + 1 * NEXP, offsb + 1 * NEXP,
                                              compactF, DMODEL, RANK);
  gather_combine<RANK, false><<<BS, 256, 0, stream>>>(compactF, w8 + 1 * wstr,
      slotmap + 1 * lstr, offsb + 1 * NEXP, nullptr, nullptr, fkb);
  wconv_kernel<<<gWF, 256, 0, stream>>>(f_v, wbuf, DMODEL, RANK);
  expert_gemm_mfma<<<gFeat, 256, 0, stream>>>(nxb, wbuf, lists + 2 * lstr,
                                              counts + 2 * NEXP, offsb + 2 * NEXP,
                                              compactF, DMODEL, RANK);
  gather_combine<RANK, false><<<BS, 256, 0, stream>>>(compactF, w8 + 2 * wstr,
      slotmap + 2 * lstr, offsb + 2 * NEXP, nullptr, nullptr, fvb);

  // restores (K=512 -> D=1024) -> bf16 Q/K/V
  wconv_kernel<<<gWR, 256, 0, stream>>>(r_qk, wbuf, RANK, DMODEL);
  expert_gemm_mfma<<<gRest, 256, 0, stream>>>(fqb, wbuf, lists + 3 * lstr,
                                              counts + 3 * NEXP, offsb + 3 * NEXP,
                                              compactR, RANK, DMODEL);
  gather_combine<DMODEL, false><<<BS, 256, 0, stream>>>(compactR, w8 + 3 * wstr,
      slotmap + 3 * lstr, offsb + 3 * NEXP, nullptr, nullptr, Qbb);
  expert_gemm_mfma<<<gRest, 256, 0, stream>>>(fkb, wbuf, lists + 4 * lstr,
                                              counts + 4 * NEXP, offsb + 4 * NEXP,
                                              compactR, RANK, DMODEL);
  gather_combine<DMODEL, false><<<BS, 256, 0, stream>>>(compactR, w8 + 4 * wstr,
      slotmap + 4 * lstr, offsb + 4 * NEXP, nullptr, nullptr, Kbb);
  wconv_kernel<<<gWR, 256, 0, stream>>>(r_v, wbuf, RANK, DMODEL);
  expert_gemm_mfma<<<gRest, 256, 0, stream>>>(fvb, wbuf, lists + 5 * lstr,
                                              counts + 5 * NEXP, offsb + 5 * NEXP,
                                              compactR, RANK, DMODEL);
  gather_combine<DMODEL, false><<<BS, 256, 0, stream>>>(compactR, w8 + 5 * wstr,
      slotmap + 5 * lstr, offsb + 5 * NEXP, nullptr, nullptr, Vbb);

  attn_mfma<<<dim3(SEQ / 64, NHEAD, BATCH), 256, 0, stream>>>(Qbb, Kbb, Vbb, attnOb);

  // x1 = x + attnO @ W_o   (bf16 MFMA)
  dense_gemm_mfma<false, true><<<dim3(DMODEL / 64, BS / 64), 256, 0, stream>>>(
      attnOb, woT, nullptr, x, x1, BS, DMODEL, DMODEL);

  // knowledge circuit
  ln_kernel<<<BS, 256, 0, stream>>>(x1, ln2s, ln2b, nx2, nxb);
  gemm_splitk<<<dim3(1, BS / 64, 8), 256, 0, stream>>>(
      nx2, W_fk, partK, BS, DSP, DMODEL, DMODEL / 8);
  reduce_bias_kernel<<<(BS * DSP / 4 + 255) / 256, 256, 0, stream>>>(
      partK, b_fk, h_fk2, BS * DSP, DSP, 8);
  route_kernel<<<BS, 64, 0, stream>>>(h_fk2, DSP, embn + 4 * NEXP * DSP, w8 + 6 * wstr);
  bucket_kernel<<<NEXP, 64, 0, stream>>>(w8 + 6 * wstr, lists + 6 * lstr,
                                         slotmap + 6 * lstr, counts + 6 * NEXP);
  gemm_splitk<<<dim3(1, BS / 64, 8), 256, 0, stream>>>(
      nx2, W_rk, partK, BS, DSP, DMODEL, DMODEL / 8);
  reduce_bias_kernel<<<(BS * DSP / 4 + 255) / 256, 256, 0, stream>>>(
      partK, b_rk, h_rk2, BS * DSP, DSP, 8);
  route_kernel<<<BS, 64, 0, stream>>>(h_rk2, DSP, embn + 5 * NEXP * DSP, w8 + 7 * wstr);
  bucket_kernel<<<NEXP, 64, 0, stream>>>(w8 + 7 * wstr, lists + 7 * lstr,
                                         slotmap + 7 * lstr, counts + 7 * NEXP);
  scan32_kernel<<<2, 64, 0, stream>>>(counts + 6 * NEXP, offsb + 6 * NEXP);

  wconv_kernel<<<gWF, 256, 0, stream>>>(f_kn, wbuf, DMODEL, RANK);
  expert_gemm_mfma<<<gFeat, 256, 0, stream>>>(nxb, wbuf, lists + 6 * lstr,
                                              counts + 6 * NEXP, offsb + 6 * NEXP,
                                              compactF, DMODEL, RANK);
  gather_combine<RANK, false><<<BS, 256, 0, stream>>>(compactF, w8 + 6 * wstr,
      slotmap + 6 * lstr, offsb + 6 * NEXP, nullptr, nullptr, fnb);
  wconv_kernel<<<gWR, 256, 0, stream>>>(r_kn, wbuf, RANK, DMODEL);
  expert_gemm_mfma<<<gRest, 256, 0, stream>>>(fnb, wbuf, lists + 7 * lstr,
                                              counts + 7 * NEXP, offsb + 7 * NEXP,
                                              compactR, RANK, DMODEL);
  // d_out = x1 + restore(featN)   (fused residual)
  gather_combine<DMODEL, true><<<BS, 256, 0, stream>>>(compactR, w8 + 7 * wstr,
      slotmap + 7 * lstr, offsb + 7 * NEXP, x1, (float*)d_out, nullptr);
}